// Round 1
// baseline (2667.629 us; speedup 1.0000x reference)
//
#include <hip/hip_runtime.h>
#include <math.h>

#define NCH 32
#define NB  16
#define HW  128
#define NPIX (HW*HW)
#define RANKK 16
#define PI_F 3.14159265358979323846f

__device__ __forceinline__ float2 cmulf(float2 a, float2 b) {
    return make_float2(a.x*b.x - a.y*b.y, a.x*b.y + a.y*b.x);
}
__device__ __forceinline__ int rev7(int i) { return (int)(__brev((unsigned)i) >> 25); }

// 128-point radix-2 DIF FFT in LDS; 64 lanes cooperate on one transform.
// sign = -1 forward, +1 inverse (unnormalized).
__device__ void fft128(float2* d, int lane, float sign) {
    for (int span = 64; span >= 1; span >>= 1) {
        int k = lane & (span - 1);
        int base = ((lane & ~(span - 1)) << 1) | k;
        float2 a = d[base];
        float2 b = d[base + span];
        float2 su = make_float2(a.x + b.x, a.y + b.y);
        float2 df = make_float2(a.x - b.x, a.y - b.y);
        float ang = sign * PI_F * (float)k / (float)span;
        float sw, cw; sincosf(ang, &sw, &cw);
        d[base] = su;
        d[base + span] = cmulf(df, make_float2(cw, sw));
        __syncthreads();
    }
    float2 v0 = d[rev7(lane)];
    float2 v1 = d[rev7(lane + 64)];
    __syncthreads();
    d[lane] = v0;
    d[lane + 64] = v1;
    __syncthreads();
}

// Forward FFT along w for every (b,c,h) row; scale by 1/128 (fft2 ortho total).
__global__ __launch_bounds__(256) void k_fwd_rows(const float* __restrict__ x,
                                                  float2* __restrict__ XF) {
    __shared__ float2 buf[4][HW];
    int wave = threadIdx.x >> 6, lane = threadIdx.x & 63;
    long row = (long)blockIdx.x * 4 + wave;
    long base = row * HW;
    const float sc = 1.0f / 128.0f;
    float2* d = buf[wave];
    d[lane]      = make_float2(x[base + lane] * sc, 0.f);
    d[lane + 64] = make_float2(x[base + lane + 64] * sc, 0.f);
    __syncthreads();
    fft128(d, lane, -1.f);
    XF[base + lane]      = d[lane];
    XF[base + lane + 64] = d[lane + 64];
}

// FFT along h, in place, 16 columns per block (tiled for coalescing).
__global__ __launch_bounds__(256) void k_cols(float2* __restrict__ XF, float sign) {
    __shared__ float2 tile[HW][16];
    int img = blockIdx.x >> 3;
    int w0  = (blockIdx.x & 7) << 4;
    long base = (long)img * NPIX + w0;
    int tid = threadIdx.x;
    for (int it = 0; it < 8; ++it) {
        int flat = it * 256 + tid;
        int h = flat >> 4, c = flat & 15;
        tile[h][c] = XF[base + (long)h * HW + c];
    }
    __syncthreads();
    for (int span = 64; span >= 1; span >>= 1) {
        for (int it = 0; it < 4; ++it) {
            int idx = it * 256 + tid;
            int j = idx >> 4, c = idx & 15;
            int k = j & (span - 1);
            int bidx = ((j & ~(span - 1)) << 1) | k;
            float2 a = tile[bidx][c], b = tile[bidx + span][c];
            float2 su = make_float2(a.x + b.x, a.y + b.y);
            float2 df = make_float2(a.x - b.x, a.y - b.y);
            float ang = sign * PI_F * (float)k / (float)span;
            float sw, cw; sincosf(ang, &sw, &cw);
            tile[bidx][c] = su;
            tile[bidx + span][c] = cmulf(df, make_float2(cw, sw));
        }
        __syncthreads();
    }
    float2 v[8];
    for (int it = 0; it < 8; ++it) {
        int flat = it * 256 + tid;
        int h = flat >> 4, c = flat & 15;
        v[it] = tile[rev7(h)][c];
    }
    __syncthreads();
    for (int it = 0; it < 8; ++it) {
        int flat = it * 256 + tid;
        int h = flat >> 4, c = flat & 15;
        tile[h][c] = v[it];
    }
    __syncthreads();
    for (int it = 0; it < 8; ++it) {
        int flat = it * 256 + tid;
        int h = flat >> 4, c = flat & 15;
        XF[base + (long)h * HW + c] = tile[h][c];
    }
}

// Per-pixel: K(h,w) -> M=KK^H -> Jacobi eigen -> P -> dist, bias(DC), y_f = conj(P) x_f.
// Hermitian symmetry: block for pixel also produces the conjugate pixel's y_f.
__global__ __launch_bounds__(128) void k_eig_apply(
    const float* __restrict__ ker, const float* __restrict__ bias,
    float2* __restrict__ XF, float* __restrict__ distP, float* __restrict__ biasp)
{
    int pix = blockIdx.x;
    int h = pix >> 7, w = pix & 127;
    int hc = (HW - h) & 127, wc = (HW - w) & 127;
    int cpix = (hc << 7) | wc;
    int tid = threadIdx.x;
    if (cpix < pix) { if (tid == 0) distP[pix] = 0.f; return; }
    bool self = (cpix == pix);

    __shared__ float2 Kf[NCH][NCH + 1];
    __shared__ float2 Mm[NCH][NCH + 1];
    __shared__ float2 Vv[NCH][NCH + 1];
    __shared__ float  cs_c[16];
    __shared__ float2 cs_s[16];
    __shared__ int    pr_p[16], pr_q[16];
    __shared__ float  evals[NCH];
    __shared__ int    sel[NCH];
    __shared__ float  red[4];
    __shared__ float  dsr[2];

    // --- K(h,w): direct 9-tap DFT of the 3x3 kernel ---
    float twr[9], twi[9];
    #pragma unroll
    for (int u = 0; u < 3; ++u)
        #pragma unroll
        for (int v2 = 0; v2 < 3; ++v2) {
            float ang = -2.0f * PI_F * (float)(h * u + w * v2) / 128.0f;
            sincosf(ang, &twi[u * 3 + v2], &twr[u * 3 + v2]);
        }
    for (int e = tid; e < NCH * NCH; e += 128) {
        int o = e >> 5, i = e & 31;
        const float* kp = ker + (size_t)(o * NCH + i) * 9;
        float ar = 0.f, ai = 0.f;
        #pragma unroll
        for (int t = 0; t < 9; ++t) { float kv = kp[t]; ar += kv * twr[t]; ai += kv * twi[t]; }
        Kf[o][i] = make_float2(ar, ai);
    }
    __syncthreads();

    // --- M = K K^H ; V = I ---
    for (int e = tid; e < NCH * NCH; e += 128) {
        int p = e >> 5, q = e & 31;
        float ar = 0.f, ai = 0.f;
        for (int i = 0; i < NCH; ++i) {
            float2 a = Kf[p][i], b = Kf[q][i];
            ar += a.x * b.x + a.y * b.y;
            ai += a.y * b.x - a.x * b.y;
        }
        Mm[p][q] = make_float2(ar, ai);
        Vv[p][q] = make_float2(p == q ? 1.f : 0.f, 0.f);
    }
    __syncthreads();

    // --- parallel-order cyclic Jacobi ---
    for (int sweep = 0; sweep < 16; ++sweep) {
        float off = 0.f, dg = 0.f;
        for (int e = tid; e < NCH * NCH; e += 128) {
            int p = e >> 5, q = e & 31;
            float2 m = Mm[p][q];
            float n = m.x * m.x + m.y * m.y;
            if (p == q) dg += n; else off += n;
        }
        #pragma unroll
        for (int msk = 32; msk >= 1; msk >>= 1) { off += __shfl_xor(off, msk); dg += __shfl_xor(dg, msk); }
        if ((tid & 63) == 0) { red[tid >> 6] = off; red[2 + (tid >> 6)] = dg; }
        __syncthreads();
        float offT = red[0] + red[1], dgT = red[2] + red[3];
        if (offT <= 1e-12f * dgT) break;

        for (int r = 0; r < 31; ++r) {
            if (tid < 16) {
                int p, q;
                if (tid == 0) { p = 31; q = r; }
                else { p = (r + tid) % 31; q = (r - tid + 31) % 31; }
                float app = Mm[p][p].x, aqq = Mm[q][q].x;
                float2 d = Mm[p][q];
                float n2 = d.x * d.x + d.y * d.y;
                float cc = 1.f; float2 ss = make_float2(0.f, 0.f);
                if (n2 > 1e-32f) {
                    float ad = sqrtf(n2);
                    float tau = (aqq - app) / (2.f * ad);
                    float tt = (tau >= 0.f ? 1.f : -1.f) / (fabsf(tau) + sqrtf(1.f + tau * tau));
                    cc = 1.f / sqrtf(1.f + tt * tt);
                    float sg = tt * cc / ad;
                    ss = make_float2(sg * d.x, sg * d.y);
                }
                cs_c[tid] = cc; cs_s[tid] = ss; pr_p[tid] = p; pr_q[tid] = q;
            }
            __syncthreads();
            // rows: T = J^H M
            for (int m = tid; m < 512; m += 128) {
                int j = m >> 5, k = m & 31;
                int p = pr_p[j], q = pr_q[j];
                float c = cs_c[j]; float2 s = cs_s[j];
                float2 a = Mm[p][k], b = Mm[q][k];
                Mm[p][k] = make_float2(c * a.x - (s.x * b.x - s.y * b.y),
                                       c * a.y - (s.x * b.y + s.y * b.x));
                Mm[q][k] = make_float2(c * b.x + (s.x * a.x + s.y * a.y),
                                       c * b.y + (s.x * a.y - s.y * a.x));
            }
            __syncthreads();
            // cols: M = T J ; V = V J
            for (int m = tid; m < 512; m += 128) {
                int j = m >> 5, k = m & 31;
                int p = pr_p[j], q = pr_q[j];
                float c = cs_c[j]; float2 s = cs_s[j];
                float2 a = Mm[k][p], b = Mm[k][q];
                Mm[k][p] = make_float2(c * a.x - (s.x * b.x + s.y * b.y),
                                       c * a.y - (s.x * b.y - s.y * b.x));
                Mm[k][q] = make_float2(c * b.x + (s.x * a.x - s.y * a.y),
                                       c * b.y + (s.x * a.y + s.y * a.x));
                float2 va = Vv[k][p], vb = Vv[k][q];
                Vv[k][p] = make_float2(c * va.x - (s.x * vb.x + s.y * vb.y),
                                       c * va.y - (s.x * vb.y - s.y * vb.x));
                Vv[k][q] = make_float2(c * vb.x + (s.x * va.x - s.y * va.y),
                                       c * vb.y + (s.x * va.y + s.y * va.x));
            }
            __syncthreads();
        }
    }

    // --- top-16 selection ---
    if (tid < NCH) evals[tid] = Mm[tid][tid].x;
    __syncthreads();
    if (tid < NCH) {
        float v = evals[tid];
        int rank = 0;
        for (int k = 0; k < NCH; ++k) {
            float u = evals[k];
            rank += (u > v || (u == v && k < tid)) ? 1 : 0;
        }
        sel[tid] = (rank < RANKK) ? 1 : 0;
    }
    __syncthreads();

    // --- P = sum_{sel j} v_j v_j^H  (into Mm), dist accumulation ---
    float ds = 0.f;
    for (int e = tid; e < NCH * NCH; e += 128) {
        int o = e >> 5, i = e & 31;
        float ar = 0.f, ai = 0.f;
        for (int j = 0; j < NCH; ++j) {
            if (sel[j]) {
                float2 a = Vv[o][j], b = Vv[i][j];
                ar += a.x * b.x + a.y * b.y;
                ai += a.y * b.x - a.x * b.y;
            }
        }
        float2 kv = Kf[o][i];
        float dx = kv.x - ar, dy = kv.y - ai;
        ds += dx * dx + dy * dy;
        Mm[o][i] = make_float2(ar, ai);   // Mm now holds P
    }
    #pragma unroll
    for (int msk = 32; msk >= 1; msk >>= 1) ds += __shfl_xor(ds, msk);
    if ((tid & 63) == 0) dsr[tid >> 6] = ds;
    __syncthreads();
    if (tid == 0) distP[pix] = (self ? 1.f : 2.f) * (dsr[0] + dsr[1]);

    // --- bias correction at DC pixel ---
    if (pix == 0 && tid < NCH) {
        float acc = 0.f;
        for (int i = 0; i < NCH; ++i) acc += Mm[tid][i].x * bias[i];
        biasp[tid] = bias[tid] - acc;
    }

    // --- spectral multiply, fused: y_f = conj(P) x_f at pix (and P x_f at cpix) ---
    float2* xb = &Kf[0][0];   // reuse Kf storage (done with K)
    for (int e = tid; e < NB * NCH; e += 128) {
        int b = e >> 5, i = e & 31;
        xb[e] = XF[(long)(b * NCH + i) * NPIX + pix];
    }
    __syncthreads();
    for (int e = tid; e < NB * NCH; e += 128) {
        int b = e >> 5, o = e & 31;
        float ar = 0.f, ai = 0.f;
        for (int i = 0; i < NCH; ++i) {
            float2 pv = Mm[o][i];
            float2 xv = xb[(b << 5) | i];
            ar += pv.x * xv.x + pv.y * xv.y;   // conj(P) * x
            ai += pv.x * xv.y - pv.y * xv.x;
        }
        XF[(long)(b * NCH + o) * NPIX + pix] = make_float2(ar, ai);
    }
    if (!self) {
        __syncthreads();
        for (int e = tid; e < NB * NCH; e += 128) {
            int b = e >> 5, i = e & 31;
            xb[e] = XF[(long)(b * NCH + i) * NPIX + cpix];
        }
        __syncthreads();
        for (int e = tid; e < NB * NCH; e += 128) {
            int b = e >> 5, o = e & 31;
            float ar = 0.f, ai = 0.f;
            for (int i = 0; i < NCH; ++i) {
                float2 pv = Mm[o][i];
                float2 xv = xb[(b << 5) | i];
                ar += pv.x * xv.x - pv.y * xv.y;   // conj(conj(P)) = P
                ai += pv.x * xv.y + pv.y * xv.x;
            }
            XF[(long)(b * NCH + o) * NPIX + cpix] = make_float2(ar, ai);
        }
    }
}

// Inverse FFT along w + take real + add bias; scale 1/128 (ifft2 ortho total).
__global__ __launch_bounds__(256) void k_inv_rows_bias(const float2* __restrict__ XF,
                                                       const float* __restrict__ biasp,
                                                       float* __restrict__ out) {
    __shared__ float2 buf[4][HW];
    int wave = threadIdx.x >> 6, lane = threadIdx.x & 63;
    long row = (long)blockIdx.x * 4 + wave;     // (b,o,h)
    int o = (int)((row >> 7) & 31);
    float bp = biasp[o];
    long base = row * HW;
    float2* d = buf[wave];
    d[lane]      = XF[base + lane];
    d[lane + 64] = XF[base + lane + 64];
    __syncthreads();
    fft128(d, lane, +1.f);
    const float sc = 1.0f / 128.0f;
    out[base + lane]      = d[lane].x * sc + bp;
    out[base + lane + 64] = d[lane + 64].x * sc + bp;
}

__global__ __launch_bounds__(256) void k_dist(const float* __restrict__ distP,
                                              float* __restrict__ out) {
    __shared__ float sh[256];
    float acc = 0.f;
    for (int i = threadIdx.x; i < NPIX; i += 256) acc += distP[i];
    sh[threadIdx.x] = acc;
    __syncthreads();
    for (int s = 128; s >= 1; s >>= 1) {
        if (threadIdx.x < s) sh[threadIdx.x] += sh[threadIdx.x + s];
        __syncthreads();
    }
    if (threadIdx.x == 0) out[(size_t)NB * NCH * NPIX] = sqrtf(sh[0]);
}

extern "C" void kernel_launch(void* const* d_in, const int* in_sizes, int n_in,
                              void* d_out, int out_size, void* d_ws, size_t ws_size,
                              hipStream_t stream) {
    (void)in_sizes; (void)n_in; (void)out_size; (void)ws_size;
    const float* x    = (const float*)d_in[0];
    const float* ker  = (const float*)d_in[1];
    const float* bias = (const float*)d_in[2];
    float* out = (float*)d_out;

    // ws layout: XF complex [16][32][128][128] (64 MiB) | distP [16384] | biasp [32]
    float2* XF   = (float2*)d_ws;
    float* distP = (float*)((char*)d_ws + (size_t)NB * NCH * NPIX * sizeof(float2));
    float* biasp = distP + NPIX;

    int rows = NB * NCH * HW;   // 65536
    k_fwd_rows<<<dim3(rows / 4), dim3(256), 0, stream>>>(x, XF);
    k_cols<<<dim3(NB * NCH * 8), dim3(256), 0, stream>>>(XF, -1.f);
    k_eig_apply<<<dim3(NPIX), dim3(128), 0, stream>>>(ker, bias, XF, distP, biasp);
    k_cols<<<dim3(NB * NCH * 8), dim3(256), 0, stream>>>(XF, +1.f);
    k_inv_rows_bias<<<dim3(rows / 4), dim3(256), 0, stream>>>(XF, biasp, out);
    k_dist<<<dim3(1), dim3(256), 0, stream>>>(distP, out);
}

// Round 2
// 2628.753 us; speedup vs baseline: 1.0148x; 1.0148x over previous
//
#include <hip/hip_runtime.h>
#include <math.h>

#define NCH 32
#define NB  16
#define HW  128
#define NPIX (HW*HW)
#define NPROB 8194
#define PI_F 3.14159265358979323846f

__device__ __forceinline__ float2 cmulf(float2 a, float2 b) {
    return make_float2(a.x*b.x - a.y*b.y, a.x*b.y + a.y*b.x);
}
__device__ __forceinline__ int rev7(int i) { return (int)(__brev((unsigned)i) >> 25); }

// 128-point radix-2 DIF FFT in LDS; 64 lanes cooperate on one transform.
__device__ void fft128(float2* d, int lane, float sign) {
    for (int span = 64; span >= 1; span >>= 1) {
        int k = lane & (span - 1);
        int base = ((lane & ~(span - 1)) << 1) | k;
        float2 a = d[base];
        float2 b = d[base + span];
        float2 su = make_float2(a.x + b.x, a.y + b.y);
        float2 df = make_float2(a.x - b.x, a.y - b.y);
        float ang = sign * PI_F * (float)k / (float)span;
        float sw, cw; sincosf(ang, &sw, &cw);
        d[base] = su;
        d[base + span] = cmulf(df, make_float2(cw, sw));
        __syncthreads();
    }
    float2 v0 = d[rev7(lane)];
    float2 v1 = d[rev7(lane + 64)];
    __syncthreads();
    d[lane] = v0;
    d[lane + 64] = v1;
    __syncthreads();
}

__global__ __launch_bounds__(256) void k_fwd_rows(const float* __restrict__ x,
                                                  float2* __restrict__ XF) {
    __shared__ float2 buf[4][HW];
    int wave = threadIdx.x >> 6, lane = threadIdx.x & 63;
    long row = (long)blockIdx.x * 4 + wave;
    long base = row * HW;
    const float sc = 1.0f / 128.0f;
    float2* d = buf[wave];
    d[lane]      = make_float2(x[base + lane] * sc, 0.f);
    d[lane + 64] = make_float2(x[base + lane + 64] * sc, 0.f);
    __syncthreads();
    fft128(d, lane, -1.f);
    XF[base + lane]      = d[lane];
    XF[base + lane + 64] = d[lane + 64];
}

__global__ __launch_bounds__(256) void k_cols(float2* __restrict__ XF, float sign) {
    __shared__ float2 tile[HW][16];
    int img = blockIdx.x >> 3;
    int w0  = (blockIdx.x & 7) << 4;
    long base = (long)img * NPIX + w0;
    int tid = threadIdx.x;
    for (int it = 0; it < 8; ++it) {
        int flat = it * 256 + tid;
        int h = flat >> 4, c = flat & 15;
        tile[h][c] = XF[base + (long)h * HW + c];
    }
    __syncthreads();
    for (int span = 64; span >= 1; span >>= 1) {
        for (int it = 0; it < 4; ++it) {
            int idx = it * 256 + tid;
            int j = idx >> 4, c = idx & 15;
            int k = j & (span - 1);
            int bidx = ((j & ~(span - 1)) << 1) | k;
            float2 a = tile[bidx][c], b = tile[bidx + span][c];
            float2 su = make_float2(a.x + b.x, a.y + b.y);
            float2 df = make_float2(a.x - b.x, a.y - b.y);
            float ang = sign * PI_F * (float)k / (float)span;
            float sw, cw; sincosf(ang, &sw, &cw);
            tile[bidx][c] = su;
            tile[bidx + span][c] = cmulf(df, make_float2(cw, sw));
        }
        __syncthreads();
    }
    float2 v[8];
    for (int it = 0; it < 8; ++it) {
        int flat = it * 256 + tid;
        int h = flat >> 4, c = flat & 15;
        v[it] = tile[rev7(h)][c];
    }
    __syncthreads();
    for (int it = 0; it < 8; ++it) {
        int flat = it * 256 + tid;
        int h = flat >> 4, c = flat & 15;
        tile[h][c] = v[it];
    }
    __syncthreads();
    for (int it = 0; it < 8; ++it) {
        int flat = it * 256 + tid;
        int h = flat >> 4, c = flat & 15;
        XF[base + (long)h * HW + c] = tile[h][c];
    }
}

__device__ __forceinline__ void prob_to_hw(int gp, int& h, int& w) {
    if (gp < 8064)      { h = 1 + (gp >> 7); w = gp & 127; }
    else if (gp < 8129) { h = 0;  w = gp - 8064; }
    else                { h = 64; w = gp - 8129; }
}

// build K column `lane`: b[o] = K_{o,lane}(h,w) via 9-tap DFT
__device__ __forceinline__ void build_kcol(const float* __restrict__ ker,
                                           int h, int w, int lane, float2* b) {
    float twr[9], twi[9];
    #pragma unroll
    for (int u = 0; u < 3; ++u)
        #pragma unroll
        for (int v = 0; v < 3; ++v) {
            float ang = -2.0f * PI_F * (float)(h * u + w * v) / 128.0f;
            sincosf(ang, &twi[u * 3 + v], &twr[u * 3 + v]);
        }
    #pragma unroll
    for (int o = 0; o < 32; ++o) {
        const float* kp = ker + (size_t)(o * NCH + lane) * 9;
        float ar = 0.f, ai = 0.f;
        #pragma unroll
        for (int t = 0; t < 9; ++t) { float kv = kp[t]; ar = fmaf(kv, twr[t], ar); ai = fmaf(kv, twi[t], ai); }
        b[o] = make_float2(ar, ai);
    }
}

__device__ __forceinline__ float halfsum(float v) {
    v += __shfl_xor(v, 1);  v += __shfl_xor(v, 2);  v += __shfl_xor(v, 4);
    v += __shfl_xor(v, 8);  v += __shfl_xor(v, 16);
    return v;
}

// One-sided Jacobi SVD per pixel, register-resident. 32 lanes per problem,
// 2 problems per wave, 1 wave per block. lane j owns column j of B=K.
__global__ __launch_bounds__(64) void k_eig_apply2(
    const float* __restrict__ ker, const float* __restrict__ bias,
    float2* __restrict__ XF, float* __restrict__ distP, float* __restrict__ biasp)
{
    __shared__ float2 U[2][16][33];   // transposed selected columns: U[half][m][i] = u_{i,m}

    int tid  = threadIdx.x;
    int half = tid >> 5, lane = tid & 31, base = half << 5;

    // XCD-bijective swizzle of 4097 blocks (q=512, r=1)
    int bid = blockIdx.x;
    int xcd = bid & 7, idx = bid >> 3;
    int bswz = (xcd == 0 ? idx : 513 + (xcd - 1) * 512 + idx);
    int gp = bswz * 2 + half;                 // 0..8193, exact
    bool active = gp < NPROB;
    int h, w; prob_to_hw(gp, h, w);
    int pix = (h << 7) | w;
    int hc = (128 - h) & 127, wc = (128 - w) & 127;
    int cpix = (hc << 7) | wc;
    bool self = (cpix == pix);

    float2 b[32];
    build_kcol(ker, h, w, lane, b);

    // ---- one-sided Jacobi: orthogonalize columns of B ----
    for (int sweep = 0; sweep < 10; ++sweep) {
        float offacc = 0.f;
        for (int r = 0; r < 31; ++r) {
            // tournament pairing on 32 items (31 fixed)
            int pj, isP;
            if (lane == 31) { pj = r; isP = 1; }
            else {
                int d = lane - r; if (d < 0) d += 31;
                if (d == 0) { pj = 31; isP = 0; }
                else if (d <= 15) { int t = r - d; if (t < 0) t += 31; pj = t; isP = 1; }
                else { int t = r + (31 - d); if (t >= 31) t -= 31; pj = t; isP = 0; }
            }
            int psrc = base + pj;

            // pass 1: 2x2 Gram of columns (p,q). Symmetric accumulators so
            // both lanes get bitwise-identical (app,aqq,gre,gim).
            float no = 0.f, nf = 0.f, gre = 0.f, A = 0.f, Bm = 0.f;
            #pragma unroll
            for (int i = 0; i < 32; ++i) {
                float fx = __shfl(b[i].x, psrc, 64);
                float fy = __shfl(b[i].y, psrc, 64);
                no  = fmaf(b[i].x, b[i].x, fmaf(b[i].y, b[i].y, no));
                nf  = fmaf(fx, fx, fmaf(fy, fy, nf));
                gre = fmaf(b[i].x, fx, fmaf(b[i].y, fy, gre));
                A   = fmaf(b[i].x, fy, A);
                Bm  = fmaf(b[i].y, fx, Bm);
            }
            float app = isP ? no : nf;
            float aqq = isP ? nf : no;
            float gim = isP ? (A - Bm) : (Bm - A);
            float n2 = gre * gre + gim * gim;
            offacc += n2;

            bool doRot = (n2 > 1e-24f * app * aqq) && (n2 > 1e-36f);
            if (__ballot(doRot)) {
                float ad  = sqrtf(n2);
                float tau = (aqq - app) / (2.f * ad);
                float tt  = (tau >= 0.f ? 1.f : -1.f) / (fabsf(tau) + sqrtf(fmaf(tau, tau, 1.f)));
                float cc  = rsqrtf(fmaf(tt, tt, 1.f));
                float sg  = tt * cc / ad;
                float ssx = sg * gre, ssy = sg * gim;
                float gx  = isP ? -ssx : ssx;   // p: -conj(s), q: s
                float gy  = ssy;
                if (!doRot) { cc = 1.f; gx = 0.f; gy = 0.f; }
                #pragma unroll
                for (int i = 0; i < 32; ++i) {
                    float fx = __shfl(b[i].x, psrc, 64);
                    float fy = __shfl(b[i].y, psrc, 64);
                    b[i].x = fmaf(cc, b[i].x, fmaf(gx, fx, -gy * fy));
                    b[i].y = fmaf(cc, b[i].y, fmaf(gx, fy,  gy * fx));
                }
            }
        }
        // convergence: sum|g_pq|^2 <= 1e-12 * sum(sigma^2)^2
        float nr = 0.f;
        #pragma unroll
        for (int i = 0; i < 32; ++i) nr = fmaf(b[i].x, b[i].x, fmaf(b[i].y, b[i].y, nr));
        float dg  = halfsum(nr * nr);
        float offT = halfsum(offacc);
        if (!__ballot(offT > 1e-12f * dg)) break;
    }

    // ---- top-16 selection by column norm, compact into LDS (normalized) ----
    float nrm = 0.f;
    #pragma unroll
    for (int i = 0; i < 32; ++i) nrm = fmaf(b[i].x, b[i].x, fmaf(b[i].y, b[i].y, nrm));
    int rank = 0;
    #pragma unroll
    for (int k = 0; k < 32; ++k) {
        float nk = __shfl(nrm, base + k, 64);
        if (nk > nrm || (nk == nrm && k < lane)) ++rank;
    }
    bool sel = rank < 16;
    unsigned long long ball = __ballot(sel);
    unsigned long long hmask = 0xFFFFFFFFull << base;
    int rsel = __popcll(ball & hmask & ((1ull << tid) - 1ull));
    float rin = rsqrtf(fmaxf(nrm, 1e-30f));
    if (sel) {
        #pragma unroll
        for (int i = 0; i < 32; ++i) U[half][rsel][i] = make_float2(b[i].x * rin, b[i].y * rin);
    }
    __syncthreads();

    // ---- spectral multiply: y = conj(P)x at pix ; y = P x at cpix (rank-16 form) ----
    for (int ph = 0; ph < 2; ++ph) {
        if (ph == 1 && self) break;
        int px = ph ? cpix : pix;
        float sgn = ph ? -1.f : 1.f;
        for (int bb = 0; bb < NB; ++bb) {
            long adr = ((long)(bb * NCH + lane)) * NPIX + px;
            float2 xr = XF[adr];
            int m = lane & 15;
            float2 c = make_float2(0.f, 0.f);
            #pragma unroll
            for (int i = 0; i < 32; ++i) {
                float xx = __shfl(xr.x, base + i, 64);
                float xy = __shfl(xr.y, base + i, 64);
                float2 ul = U[half][m][i];
                float uy = sgn * ul.y;
                c.x = fmaf(ul.x, xx, fmaf(-uy, xy, c.x));
                c.y = fmaf(ul.x, xy, fmaf( uy, xx, c.y));
            }
            float2 y = make_float2(0.f, 0.f);
            #pragma unroll
            for (int mm = 0; mm < 16; ++mm) {
                float cx = __shfl(c.x, base + mm, 64);
                float cy = __shfl(c.y, base + mm, 64);
                float2 ul = U[half][mm][lane];
                float uy = sgn * ul.y;
                y.x = fmaf(ul.x, cx, fmaf( uy, cy, y.x));
                y.y = fmaf(ul.x, cy, fmaf(-uy, cx, y.y));
            }
            if (active) XF[adr] = y;
        }
    }

    // ---- dist: ||K-P||^2 = ||K||^2 - 2 Re tr(K^H P) + 16 ----
    build_kcol(ker, h, w, lane, b);   // rebuild original K column
    float kn = 0.f;
    #pragma unroll
    for (int i = 0; i < 32; ++i) kn = fmaf(b[i].x, b[i].x, fmaf(b[i].y, b[i].y, kn));
    float knt = halfsum(kn);
    float tr = 0.f;
    #pragma unroll
    for (int m = 0; m < 16; ++m) {
        float2 acc = make_float2(0.f, 0.f);
        #pragma unroll
        for (int rr = 0; rr < 32; ++rr) {
            float2 um = U[half][m][rr];            // broadcast read
            acc.x = fmaf(b[rr].x, um.x, fmaf( b[rr].y, um.y, acc.x));  // conj(K_col) . u_m
            acc.y = fmaf(b[rr].x, um.y, fmaf(-b[rr].y, um.x, acc.y));
        }
        float2 w0 = U[half][m][lane];
        tr += w0.x * acc.x + w0.y * acc.y;          // Re(conj(u_om) * acc_o)
    }
    float trt = halfsum(tr);
    if (active && lane == 0) {
        float d2 = knt - 2.f * trt + 16.f;
        distP[gp] = (self ? 1.f : 2.f) * d2;
    }

    // ---- bias correction at DC pixel (gp==8064 -> (h,w)=(0,0)) ----
    if (active && gp == 8064) {
        int m = lane & 15;
        float2 d = make_float2(0.f, 0.f);
        #pragma unroll
        for (int i = 0; i < 32; ++i) {
            float bv = bias[i];
            float2 ul = U[half][m][i];
            d.x = fmaf(ul.x, bv, d.x);
            d.y = fmaf(-ul.y, bv, d.y);             // conj(u) * bias
        }
        float racc = 0.f;
        #pragma unroll
        for (int mm = 0; mm < 16; ++mm) {
            float dx = __shfl(d.x, base + mm, 64);
            float dy = __shfl(d.y, base + mm, 64);
            float2 ul = U[half][mm][lane];
            racc = fmaf(ul.x, dx, fmaf(-ul.y, dy, racc));   // Re(u * d)
        }
        biasp[lane] = bias[lane] - racc;
    }
}

__global__ __launch_bounds__(256) void k_inv_rows_bias(const float2* __restrict__ XF,
                                                       const float* __restrict__ biasp,
                                                       float* __restrict__ out) {
    __shared__ float2 buf[4][HW];
    int wave = threadIdx.x >> 6, lane = threadIdx.x & 63;
    long row = (long)blockIdx.x * 4 + wave;     // (b,o,h)
    int o = (int)((row >> 7) & 31);
    float bp = biasp[o];
    long base = row * HW;
    float2* d = buf[wave];
    d[lane]      = XF[base + lane];
    d[lane + 64] = XF[base + lane + 64];
    __syncthreads();
    fft128(d, lane, +1.f);
    const float sc = 1.0f / 128.0f;
    out[base + lane]      = d[lane].x * sc + bp;
    out[base + lane + 64] = d[lane + 64].x * sc + bp;
}

__global__ __launch_bounds__(256) void k_dist(const float* __restrict__ distP,
                                              float* __restrict__ out) {
    __shared__ float sh[256];
    float acc = 0.f;
    for (int i = threadIdx.x; i < NPROB; i += 256) acc += distP[i];
    sh[threadIdx.x] = acc;
    __syncthreads();
    for (int s = 128; s >= 1; s >>= 1) {
        if (threadIdx.x < s) sh[threadIdx.x] += sh[threadIdx.x + s];
        __syncthreads();
    }
    if (threadIdx.x == 0) out[(size_t)NB * NCH * NPIX] = sqrtf(sh[0]);
}

extern "C" void kernel_launch(void* const* d_in, const int* in_sizes, int n_in,
                              void* d_out, int out_size, void* d_ws, size_t ws_size,
                              hipStream_t stream) {
    (void)in_sizes; (void)n_in; (void)out_size; (void)ws_size;
    const float* x    = (const float*)d_in[0];
    const float* ker  = (const float*)d_in[1];
    const float* bias = (const float*)d_in[2];
    float* out = (float*)d_out;

    // ws: XF complex [16][32][128][128] (64 MiB) | distP [8194] | biasp [32]
    float2* XF   = (float2*)d_ws;
    float* distP = (float*)((char*)d_ws + (size_t)NB * NCH * NPIX * sizeof(float2));
    float* biasp = distP + NPROB;

    int rows = NB * NCH * HW;   // 65536
    k_fwd_rows<<<dim3(rows / 4), dim3(256), 0, stream>>>(x, XF);
    k_cols<<<dim3(NB * NCH * 8), dim3(256), 0, stream>>>(XF, -1.f);
    k_eig_apply2<<<dim3(4097), dim3(64), 0, stream>>>(ker, bias, XF, distP, biasp);
    k_cols<<<dim3(NB * NCH * 8), dim3(256), 0, stream>>>(XF, +1.f);
    k_inv_rows_bias<<<dim3(rows / 4), dim3(256), 0, stream>>>(XF, biasp, out);
    k_dist<<<dim3(1), dim3(256), 0, stream>>>(distP, out);
}

// Round 3
// 2092.679 us; speedup vs baseline: 1.2747x; 1.2562x over previous
//
#include <hip/hip_runtime.h>
#include <math.h>

#define NCH 32
#define NB  16
#define HW  128
#define NPIX (HW*HW)
#define NPROB 8194
#define PI_F 3.14159265358979323846f

__device__ __forceinline__ float2 cmulf(float2 a, float2 b) {
    return make_float2(a.x*b.x - a.y*b.y, a.x*b.y + a.y*b.x);
}
__device__ __forceinline__ int rev7(int i) { return (int)(__brev((unsigned)i) >> 25); }
// HW trig: input in revolutions (angle/2pi). Exact for dyadic-rational inputs.
__device__ __forceinline__ float hw_sin(float rev) { return __builtin_amdgcn_sinf(rev); }
__device__ __forceinline__ float hw_cos(float rev) { return __builtin_amdgcn_cosf(rev); }

// 128-point radix-2 DIF FFT in LDS; 64 lanes cooperate on one transform.
__device__ void fft128(float2* d, int lane, float sign) {
    for (int span = 64; span >= 1; span >>= 1) {
        int k = lane & (span - 1);
        int base = ((lane & ~(span - 1)) << 1) | k;
        float2 a = d[base];
        float2 b = d[base + span];
        float2 su = make_float2(a.x + b.x, a.y + b.y);
        float2 df = make_float2(a.x - b.x, a.y - b.y);
        float rev = (float)k / (float)(2 * span);      // |ang| = 2*pi*rev
        float cw = hw_cos(rev);
        float sw = sign * hw_sin(rev);
        d[base] = su;
        d[base + span] = cmulf(df, make_float2(cw, sw));
        __syncthreads();
    }
    float2 v0 = d[rev7(lane)];
    float2 v1 = d[rev7(lane + 64)];
    __syncthreads();
    d[lane] = v0;
    d[lane + 64] = v1;
    __syncthreads();
}

__global__ __launch_bounds__(256) void k_fwd_rows(const float* __restrict__ x,
                                                  float2* __restrict__ XF) {
    __shared__ float2 buf[4][HW];
    int wave = threadIdx.x >> 6, lane = threadIdx.x & 63;
    long row = (long)blockIdx.x * 4 + wave;
    long base = row * HW;
    const float sc = 1.0f / 128.0f;
    float2* d = buf[wave];
    d[lane]      = make_float2(x[base + lane] * sc, 0.f);
    d[lane + 64] = make_float2(x[base + lane + 64] * sc, 0.f);
    __syncthreads();
    fft128(d, lane, -1.f);
    XF[base + lane]      = d[lane];
    XF[base + lane + 64] = d[lane + 64];
}

__global__ __launch_bounds__(256) void k_cols(float2* __restrict__ XF, float sign) {
    __shared__ float2 tile[HW][17];
    int img = blockIdx.x >> 3;
    int w0  = (blockIdx.x & 7) << 4;
    long base = (long)img * NPIX + w0;
    int tid = threadIdx.x;
    for (int it = 0; it < 8; ++it) {
        int flat = it * 256 + tid;
        int h = flat >> 4, c = flat & 15;
        tile[h][c] = XF[base + (long)h * HW + c];
    }
    __syncthreads();
    for (int span = 64; span >= 1; span >>= 1) {
        for (int it = 0; it < 4; ++it) {
            int idx = it * 256 + tid;
            int j = idx >> 4, c = idx & 15;
            int k = j & (span - 1);
            int bidx = ((j & ~(span - 1)) << 1) | k;
            float2 a = tile[bidx][c], b = tile[bidx + span][c];
            float2 su = make_float2(a.x + b.x, a.y + b.y);
            float2 df = make_float2(a.x - b.x, a.y - b.y);
            float rev = (float)k / (float)(2 * span);
            float cw = hw_cos(rev);
            float sw = sign * hw_sin(rev);
            tile[bidx][c] = su;
            tile[bidx + span][c] = cmulf(df, make_float2(cw, sw));
        }
        __syncthreads();
    }
    float2 v[8];
    for (int it = 0; it < 8; ++it) {
        int flat = it * 256 + tid;
        int h = flat >> 4, c = flat & 15;
        v[it] = tile[rev7(h)][c];
    }
    __syncthreads();
    for (int it = 0; it < 8; ++it) {
        int flat = it * 256 + tid;
        int h = flat >> 4, c = flat & 15;
        tile[h][c] = v[it];
    }
    __syncthreads();
    for (int it = 0; it < 8; ++it) {
        int flat = it * 256 + tid;
        int h = flat >> 4, c = flat & 15;
        XF[base + (long)h * HW + c] = tile[h][c];
    }
}

__device__ __forceinline__ void prob_to_hw(int gp, int& h, int& w) {
    if (gp < 8064)      { h = 1 + (gp >> 7); w = gp & 127; }
    else if (gp < 8129) { h = 0;  w = gp - 8064; }
    else                { h = 64; w = gp - 8129; }
}

// build K column `lane`: b[o] = K_{o,lane}(h,w) via 9-tap DFT (HW trig, exact angles)
__device__ __forceinline__ void build_kcol(const float* __restrict__ ker,
                                           int h, int w, int lane, float2* b) {
    float twr[9], twi[9];
    #pragma unroll
    for (int u = 0; u < 3; ++u)
        #pragma unroll
        for (int v = 0; v < 3; ++v) {
            int idx = (h * u + w * v) & 127;
            float rev = (float)idx * (1.0f / 128.0f);
            twr[u * 3 + v] =  hw_cos(rev);
            twi[u * 3 + v] = -hw_sin(rev);
        }
    #pragma unroll
    for (int o = 0; o < 32; ++o) {
        const float* kp = ker + (size_t)(o * NCH + lane) * 9;
        float ar = 0.f, ai = 0.f;
        #pragma unroll
        for (int t = 0; t < 9; ++t) { float kv = kp[t]; ar = fmaf(kv, twr[t], ar); ai = fmaf(kv, twi[t], ai); }
        b[o] = make_float2(ar, ai);
    }
}

__device__ __forceinline__ float halfsum(float v) {
    v += __shfl_xor(v, 1);  v += __shfl_xor(v, 2);  v += __shfl_xor(v, 4);
    v += __shfl_xor(v, 8);  v += __shfl_xor(v, 16);
    return v;
}

// One-sided Jacobi SVD per pixel, register-resident. 32 lanes per problem,
// 2 problems per wave, 4 waves (8 problems) per block. Waves fully independent.
__global__ __launch_bounds__(256, 4) void k_eig_apply3(
    const float* __restrict__ ker, const float* __restrict__ bias,
    float2* __restrict__ XF, float* __restrict__ distP, float* __restrict__ biasp)
{
    __shared__ float2 U[8][16][33];   // per-problem slice, same-wave use only

    int tid   = threadIdx.x;
    int l64   = tid & 63;             // lane in wave
    int half  = l64 >> 5;
    int lane  = l64 & 31;
    int sbase = half << 5;            // shfl base within wave
    int slot  = tid >> 5;             // 0..7, U slice / problem slot in block

    int gp = blockIdx.x * 8 + slot;
    bool active = gp < NPROB;
    int gpe = active ? gp : 0;
    int h, w; prob_to_hw(gpe, h, w);
    int pix = (h << 7) | w;
    int hc = (128 - h) & 127, wc = (128 - w) & 127;
    int cpix = (hc << 7) | wc;
    bool self = (cpix == pix);

    float2 b[32];
    build_kcol(ker, h, w, lane, b);

    // ---- one-sided Jacobi, XOR-pair ordering (masks 1..31 = all 496 pairs) ----
    for (int sweep = 0; sweep < 8; ++sweep) {
        float offacc = 0.f;
        for (int m = 1; m < 32; ++m) {
            bool isP = lane < (lane ^ m);
            // 2x2 Gram of the pair; symmetric accumulators -> both lanes get
            // bitwise-identical (gre, |gim|) so rotations agree exactly.
            float no = 0.f, gre = 0.f, A = 0.f, Bm = 0.f;
            #pragma unroll
            for (int i = 0; i < 32; ++i) {
                float fx = __shfl_xor(b[i].x, m, 64);
                float fy = __shfl_xor(b[i].y, m, 64);
                no  = fmaf(b[i].x, b[i].x, fmaf(b[i].y, b[i].y, no));
                gre = fmaf(b[i].x, fx, fmaf(b[i].y, fy, gre));
                A   = fmaf(b[i].x, fy, A);
                Bm  = fmaf(b[i].y, fx, Bm);
            }
            float nf = __shfl_xor(no, m, 64);
            float app = isP ? no : nf;
            float aqq = isP ? nf : no;
            float gim = isP ? (A - Bm) : (Bm - A);
            float n2 = gre * gre + gim * gim;
            offacc += n2;

            bool doRot = (n2 > 1e-24f * app * aqq) && (n2 > 1e-36f);
            if (__ballot(doRot)) {
                float ad  = sqrtf(n2);
                float tau = (aqq - app) / (2.f * ad);
                float tt  = (tau >= 0.f ? 1.f : -1.f) / (fabsf(tau) + sqrtf(fmaf(tau, tau, 1.f)));
                float cc  = rsqrtf(fmaf(tt, tt, 1.f));
                float sg  = tt * cc / ad;
                float ssx = sg * gre, ssy = sg * gim;
                float gx  = isP ? -ssx : ssx;   // p: -conj(s), q: +s
                float gy  = ssy;
                if (!doRot) { cc = 1.f; gx = 0.f; gy = 0.f; }
                #pragma unroll
                for (int i = 0; i < 32; ++i) {
                    float fx = __shfl_xor(b[i].x, m, 64);
                    float fy = __shfl_xor(b[i].y, m, 64);
                    b[i].x = fmaf(cc, b[i].x, fmaf(gx, fx, -gy * fy));
                    b[i].y = fmaf(cc, b[i].y, fmaf(gx, fy,  gy * fx));
                }
            }
        }
        // convergence: sum|g_pq|^2 <= 1e-12 * (sum sigma^2)^2
        float nr = 0.f;
        #pragma unroll
        for (int i = 0; i < 32; ++i) nr = fmaf(b[i].x, b[i].x, fmaf(b[i].y, b[i].y, nr));
        float dg   = halfsum(nr * nr);
        float offT = halfsum(offacc);
        if (!__ballot(offT > 1e-12f * dg)) break;
    }

    // ---- top-16 selection by column norm, compact (normalized) into LDS ----
    float nrm = 0.f;
    #pragma unroll
    for (int i = 0; i < 32; ++i) nrm = fmaf(b[i].x, b[i].x, fmaf(b[i].y, b[i].y, nrm));
    int rank = 0;
    #pragma unroll
    for (int k = 0; k < 32; ++k) {
        float nk = __shfl(nrm, sbase + k, 64);
        if (nk > nrm || (nk == nrm && k < lane)) ++rank;
    }
    bool sel = rank < 16;
    unsigned long long ball = __ballot(sel);
    int rsel = __popcll(ball & (0xFFFFFFFFull << (half * 32)) & ((1ull << l64) - 1ull));
    float rin = rsqrtf(fmaxf(nrm, 1e-30f));
    if (sel) {
        #pragma unroll
        for (int i = 0; i < 32; ++i) U[slot][rsel][i] = make_float2(b[i].x * rin, b[i].y * rin);
    }
    // wave-local fence: U writes visible to this wave's later reads (DS pipe is
    // in-order per wave; fence stops compiler reordering). No cross-wave sharing.
    asm volatile("s_waitcnt lgkmcnt(0)" ::: "memory");
    __builtin_amdgcn_sched_barrier(0);

    // ---- spectral multiply: y = conj(P)x at pix ; y = P x at cpix (rank-16) ----
    for (int ph = 0; ph < 2; ++ph) {
        if (ph == 1 && self) break;
        int px = ph ? cpix : pix;
        float sgn = ph ? -1.f : 1.f;
        for (int bb = 0; bb < NB; ++bb) {
            long adr = ((long)(bb * NCH + lane)) * NPIX + px;
            float2 xr = XF[adr];
            int mmode = lane & 15;
            float2 c = make_float2(0.f, 0.f);
            #pragma unroll
            for (int i = 0; i < 32; ++i) {
                float xx = __shfl(xr.x, sbase + i, 64);
                float xy = __shfl(xr.y, sbase + i, 64);
                float2 ul = U[slot][mmode][i];
                float uy = sgn * ul.y;
                c.x = fmaf(ul.x, xx, fmaf(-uy, xy, c.x));
                c.y = fmaf(ul.x, xy, fmaf( uy, xx, c.y));
            }
            float2 y = make_float2(0.f, 0.f);
            #pragma unroll
            for (int mm = 0; mm < 16; ++mm) {
                float cx = __shfl(c.x, sbase + mm, 64);
                float cy = __shfl(c.y, sbase + mm, 64);
                float2 ul = U[slot][mm][lane];
                float uy = sgn * ul.y;
                y.x = fmaf(ul.x, cx, fmaf( uy, cy, y.x));
                y.y = fmaf(ul.x, cy, fmaf(-uy, cx, y.y));
            }
            if (active) XF[adr] = y;
        }
    }

    // ---- dist: ||K-P||^2 = ||K||^2 - 2 Re tr(K^H P) + 16 ----
    build_kcol(ker, h, w, lane, b);   // rebuild original K column
    float kn = 0.f;
    #pragma unroll
    for (int i = 0; i < 32; ++i) kn = fmaf(b[i].x, b[i].x, fmaf(b[i].y, b[i].y, kn));
    float knt = halfsum(kn);
    float tr = 0.f;
    #pragma unroll
    for (int m = 0; m < 16; ++m) {
        float2 acc = make_float2(0.f, 0.f);
        #pragma unroll
        for (int rr = 0; rr < 32; ++rr) {
            float2 um = U[slot][m][rr];            // broadcast read
            acc.x = fmaf(b[rr].x, um.x, fmaf( b[rr].y, um.y, acc.x));  // conj(K_col).u_m
            acc.y = fmaf(b[rr].x, um.y, fmaf(-b[rr].y, um.x, acc.y));
        }
        float2 w0 = U[slot][m][lane];
        tr += w0.x * acc.x + w0.y * acc.y;          // Re(conj(u_om) * acc_o)
    }
    float trt = halfsum(tr);
    if (active && lane == 0) {
        float d2 = knt - 2.f * trt + 16.f;
        distP[gp] = (self ? 1.f : 2.f) * d2;
    }

    // ---- bias correction at DC pixel (gp==8064 -> (h,w)=(0,0)) ----
    if (active && gp == 8064) {
        int mmode = lane & 15;
        float2 d = make_float2(0.f, 0.f);
        #pragma unroll
        for (int i = 0; i < 32; ++i) {
            float bv = bias[i];
            float2 ul = U[slot][mmode][i];
            d.x = fmaf(ul.x, bv, d.x);
            d.y = fmaf(-ul.y, bv, d.y);             // conj(u) * bias
        }
        float racc = 0.f;
        #pragma unroll
        for (int mm = 0; mm < 16; ++mm) {
            float dx = __shfl(d.x, sbase + mm, 64);
            float dy = __shfl(d.y, sbase + mm, 64);
            float2 ul = U[slot][mm][lane];
            racc = fmaf(ul.x, dx, fmaf(-ul.y, dy, racc));   // Re(u * d)
        }
        biasp[lane] = bias[lane] - racc;
    }
}

__global__ __launch_bounds__(256) void k_inv_rows_bias(const float2* __restrict__ XF,
                                                       const float* __restrict__ biasp,
                                                       float* __restrict__ out) {
    __shared__ float2 buf[4][HW];
    int wave = threadIdx.x >> 6, lane = threadIdx.x & 63;
    long row = (long)blockIdx.x * 4 + wave;     // (b,o,h)
    int o = (int)((row >> 7) & 31);
    float bp = biasp[o];
    long base = row * HW;
    float2* d = buf[wave];
    d[lane]      = XF[base + lane];
    d[lane + 64] = XF[base + lane + 64];
    __syncthreads();
    fft128(d, lane, +1.f);
    const float sc = 1.0f / 128.0f;
    out[base + lane]      = d[lane].x * sc + bp;
    out[base + lane + 64] = d[lane + 64].x * sc + bp;
}

__global__ __launch_bounds__(256) void k_dist(const float* __restrict__ distP,
                                              float* __restrict__ out) {
    __shared__ float sh[256];
    float acc = 0.f;
    for (int i = threadIdx.x; i < NPROB; i += 256) acc += distP[i];
    sh[threadIdx.x] = acc;
    __syncthreads();
    for (int s = 128; s >= 1; s >>= 1) {
        if (threadIdx.x < s) sh[threadIdx.x] += sh[threadIdx.x + s];
        __syncthreads();
    }
    if (threadIdx.x == 0) out[(size_t)NB * NCH * NPIX] = sqrtf(sh[0]);
}

extern "C" void kernel_launch(void* const* d_in, const int* in_sizes, int n_in,
                              void* d_out, int out_size, void* d_ws, size_t ws_size,
                              hipStream_t stream) {
    (void)in_sizes; (void)n_in; (void)out_size; (void)ws_size;
    const float* x    = (const float*)d_in[0];
    const float* ker  = (const float*)d_in[1];
    const float* bias = (const float*)d_in[2];
    float* out = (float*)d_out;

    // ws: XF complex [16][32][128][128] (64 MiB) | distP [8194] | biasp [32]
    float2* XF   = (float2*)d_ws;
    float* distP = (float*)((char*)d_ws + (size_t)NB * NCH * NPIX * sizeof(float2));
    float* biasp = distP + NPROB;

    int rows = NB * NCH * HW;   // 65536
    k_fwd_rows<<<dim3(rows / 4), dim3(256), 0, stream>>>(x, XF);
    k_cols<<<dim3(NB * NCH * 8), dim3(256), 0, stream>>>(XF, -1.f);
    k_eig_apply3<<<dim3(1025), dim3(256), 0, stream>>>(ker, bias, XF, distP, biasp);
    k_cols<<<dim3(NB * NCH * 8), dim3(256), 0, stream>>>(XF, +1.f);
    k_inv_rows_bias<<<dim3(rows / 4), dim3(256), 0, stream>>>(XF, biasp, out);
    k_dist<<<dim3(1), dim3(256), 0, stream>>>(distP, out);
}

// Round 4
// 1926.899 us; speedup vs baseline: 1.3844x; 1.0860x over previous
//
#include <hip/hip_runtime.h>
#include <math.h>

#define NCH 32
#define NB  16
#define HW  128
#define NPIX (HW*HW)
#define NPROB 8194
#define PI_F 3.14159265358979323846f

__device__ __forceinline__ float2 cmulf(float2 a, float2 b) {
    return make_float2(a.x*b.x - a.y*b.y, a.x*b.y + a.y*b.x);
}
__device__ __forceinline__ int rev7(int i) { return (int)(__brev((unsigned)i) >> 25); }
// HW trig: input in revolutions (angle/2pi). Exact for dyadic-rational inputs.
__device__ __forceinline__ float hw_sin(float rev) { return __builtin_amdgcn_sinf(rev); }
__device__ __forceinline__ float hw_cos(float rev) { return __builtin_amdgcn_cosf(rev); }

// 128-point radix-2 DIF FFT in LDS; 64 lanes cooperate on one transform.
__device__ void fft128(float2* d, int lane, float sign) {
    for (int span = 64; span >= 1; span >>= 1) {
        int k = lane & (span - 1);
        int base = ((lane & ~(span - 1)) << 1) | k;
        float2 a = d[base];
        float2 b = d[base + span];
        float2 su = make_float2(a.x + b.x, a.y + b.y);
        float2 df = make_float2(a.x - b.x, a.y - b.y);
        float rev = (float)k / (float)(2 * span);      // |ang| = 2*pi*rev
        float cw = hw_cos(rev);
        float sw = sign * hw_sin(rev);
        d[base] = su;
        d[base + span] = cmulf(df, make_float2(cw, sw));
        __syncthreads();
    }
    float2 v0 = d[rev7(lane)];
    float2 v1 = d[rev7(lane + 64)];
    __syncthreads();
    d[lane] = v0;
    d[lane + 64] = v1;
    __syncthreads();
}

__global__ __launch_bounds__(256) void k_fwd_rows(const float* __restrict__ x,
                                                  float2* __restrict__ XF) {
    __shared__ float2 buf[4][HW];
    int wave = threadIdx.x >> 6, lane = threadIdx.x & 63;
    long row = (long)blockIdx.x * 4 + wave;
    long base = row * HW;
    const float sc = 1.0f / 128.0f;
    float2* d = buf[wave];
    d[lane]      = make_float2(x[base + lane] * sc, 0.f);
    d[lane + 64] = make_float2(x[base + lane + 64] * sc, 0.f);
    __syncthreads();
    fft128(d, lane, -1.f);
    XF[base + lane]      = d[lane];
    XF[base + lane + 64] = d[lane + 64];
}

__global__ __launch_bounds__(256) void k_cols(float2* __restrict__ XF, float sign) {
    __shared__ float2 tile[HW][17];
    int img = blockIdx.x >> 3;
    int w0  = (blockIdx.x & 7) << 4;
    long base = (long)img * NPIX + w0;
    int tid = threadIdx.x;
    for (int it = 0; it < 8; ++it) {
        int flat = it * 256 + tid;
        int h = flat >> 4, c = flat & 15;
        tile[h][c] = XF[base + (long)h * HW + c];
    }
    __syncthreads();
    for (int span = 64; span >= 1; span >>= 1) {
        for (int it = 0; it < 4; ++it) {
            int idx = it * 256 + tid;
            int j = idx >> 4, c = idx & 15;
            int k = j & (span - 1);
            int bidx = ((j & ~(span - 1)) << 1) | k;
            float2 a = tile[bidx][c], b = tile[bidx + span][c];
            float2 su = make_float2(a.x + b.x, a.y + b.y);
            float2 df = make_float2(a.x - b.x, a.y - b.y);
            float rev = (float)k / (float)(2 * span);
            float cw = hw_cos(rev);
            float sw = sign * hw_sin(rev);
            tile[bidx][c] = su;
            tile[bidx + span][c] = cmulf(df, make_float2(cw, sw));
        }
        __syncthreads();
    }
    float2 v[8];
    for (int it = 0; it < 8; ++it) {
        int flat = it * 256 + tid;
        int h = flat >> 4, c = flat & 15;
        v[it] = tile[rev7(h)][c];
    }
    __syncthreads();
    for (int it = 0; it < 8; ++it) {
        int flat = it * 256 + tid;
        int h = flat >> 4, c = flat & 15;
        tile[h][c] = v[it];
    }
    __syncthreads();
    for (int it = 0; it < 8; ++it) {
        int flat = it * 256 + tid;
        int h = flat >> 4, c = flat & 15;
        XF[base + (long)h * HW + c] = tile[h][c];
    }
}

__device__ __forceinline__ void prob_to_hw(int gp, int& h, int& w) {
    if (gp < 8064)      { h = 1 + (gp >> 7); w = gp & 127; }
    else if (gp < 8129) { h = 0;  w = gp - 8064; }
    else                { h = 64; w = gp - 8129; }
}

// build K column `lane`: b[o] = K_{o,lane}(h,w) via 9-tap DFT (HW trig, exact angles)
__device__ __forceinline__ void build_kcol(const float* __restrict__ ker,
                                           int h, int w, int lane, float2* b) {
    float twr[9], twi[9];
    #pragma unroll
    for (int u = 0; u < 3; ++u)
        #pragma unroll
        for (int v = 0; v < 3; ++v) {
            int idx = (h * u + w * v) & 127;
            float rev = (float)idx * (1.0f / 128.0f);
            twr[u * 3 + v] =  hw_cos(rev);
            twi[u * 3 + v] = -hw_sin(rev);
        }
    #pragma unroll
    for (int o = 0; o < 32; ++o) {
        const float* kp = ker + (size_t)(o * NCH + lane) * 9;
        float ar = 0.f, ai = 0.f;
        #pragma unroll
        for (int t = 0; t < 9; ++t) { float kv = kp[t]; ar = fmaf(kv, twr[t], ar); ai = fmaf(kv, twi[t], ai); }
        b[o] = make_float2(ar, ai);
    }
}

__device__ __forceinline__ float halfsum(float v) {
    v += __shfl_xor(v, 1);  v += __shfl_xor(v, 2);  v += __shfl_xor(v, 4);
    v += __shfl_xor(v, 8);  v += __shfl_xor(v, 16);
    return v;
}

// One-sided Jacobi SVD per pixel, register-resident. 32 lanes per problem,
// 2 problems per wave, 4 waves (8 problems) per block. Waves fully independent.
// (256,3): VGPR cap ~170 >= natural ~160 -> NO spill (the (256,4) variant
// spilled: VGPR 64, +1 GB scratch HBM traffic). 3 waves/SIMD.
__global__ __launch_bounds__(256, 3) void k_eig_apply3(
    const float* __restrict__ ker, const float* __restrict__ bias,
    float2* __restrict__ XF, float* __restrict__ distP, float* __restrict__ biasp)
{
    __shared__ float2 U[8][16][33];   // per-problem slice, same-wave use only

    int tid   = threadIdx.x;
    int l64   = tid & 63;             // lane in wave
    int half  = l64 >> 5;
    int lane  = l64 & 31;
    int sbase = half << 5;            // shfl base within wave
    int slot  = tid >> 5;             // 0..7, U slice / problem slot in block

    int gp = blockIdx.x * 8 + slot;
    bool active = gp < NPROB;
    int gpe = active ? gp : 0;
    int h, w; prob_to_hw(gpe, h, w);
    int pix = (h << 7) | w;
    int hc = (128 - h) & 127, wc = (128 - w) & 127;
    int cpix = (hc << 7) | wc;
    bool self = (cpix == pix);

    float2 b[32];
    build_kcol(ker, h, w, lane, b);

    // ---- one-sided Jacobi, XOR-pair ordering (masks 1..31 = all 496 pairs) ----
    for (int sweep = 0; sweep < 8; ++sweep) {
        float offacc = 0.f;
        for (int m = 1; m < 32; ++m) {
            bool isP = lane < (lane ^ m);
            // 2x2 Gram of the pair; symmetric accumulators -> both lanes get
            // bitwise-identical (gre, |gim|) so rotations agree exactly.
            float no = 0.f, gre = 0.f, A = 0.f, Bm = 0.f;
            #pragma unroll
            for (int i = 0; i < 32; ++i) {
                float fx = __shfl_xor(b[i].x, m, 64);
                float fy = __shfl_xor(b[i].y, m, 64);
                no  = fmaf(b[i].x, b[i].x, fmaf(b[i].y, b[i].y, no));
                gre = fmaf(b[i].x, fx, fmaf(b[i].y, fy, gre));
                A   = fmaf(b[i].x, fy, A);
                Bm  = fmaf(b[i].y, fx, Bm);
            }
            float nf = __shfl_xor(no, m, 64);
            float app = isP ? no : nf;
            float aqq = isP ? nf : no;
            float gim = isP ? (A - Bm) : (Bm - A);
            float n2 = gre * gre + gim * gim;
            offacc += n2;

            bool doRot = (n2 > 1e-24f * app * aqq) && (n2 > 1e-36f);
            if (__ballot(doRot)) {
                float ad  = sqrtf(n2);
                float tau = (aqq - app) / (2.f * ad);
                float tt  = (tau >= 0.f ? 1.f : -1.f) / (fabsf(tau) + sqrtf(fmaf(tau, tau, 1.f)));
                float cc  = rsqrtf(fmaf(tt, tt, 1.f));
                float sg  = tt * cc / ad;
                float ssx = sg * gre, ssy = sg * gim;
                float gx  = isP ? -ssx : ssx;   // p: -conj(s), q: +s
                float gy  = ssy;
                if (!doRot) { cc = 1.f; gx = 0.f; gy = 0.f; }
                #pragma unroll
                for (int i = 0; i < 32; ++i) {
                    float fx = __shfl_xor(b[i].x, m, 64);
                    float fy = __shfl_xor(b[i].y, m, 64);
                    b[i].x = fmaf(cc, b[i].x, fmaf(gx, fx, -gy * fy));
                    b[i].y = fmaf(cc, b[i].y, fmaf(gx, fy,  gy * fx));
                }
            }
        }
        // convergence: sum|g_pq|^2 <= 1e-12 * (sum sigma^2)^2
        float nr = 0.f;
        #pragma unroll
        for (int i = 0; i < 32; ++i) nr = fmaf(b[i].x, b[i].x, fmaf(b[i].y, b[i].y, nr));
        float dg   = halfsum(nr * nr);
        float offT = halfsum(offacc);
        if (!__ballot(offT > 1e-12f * dg)) break;
    }

    // ---- top-16 selection by column norm, compact (normalized) into LDS ----
    float nrm = 0.f;
    #pragma unroll
    for (int i = 0; i < 32; ++i) nrm = fmaf(b[i].x, b[i].x, fmaf(b[i].y, b[i].y, nrm));
    int rank = 0;
    #pragma unroll
    for (int k = 0; k < 32; ++k) {
        float nk = __shfl(nrm, sbase + k, 64);
        if (nk > nrm || (nk == nrm && k < lane)) ++rank;
    }
    bool sel = rank < 16;
    unsigned long long ball = __ballot(sel);
    int rsel = __popcll(ball & (0xFFFFFFFFull << (half * 32)) & ((1ull << l64) - 1ull));
    float rin = rsqrtf(fmaxf(nrm, 1e-30f));
    if (sel) {
        #pragma unroll
        for (int i = 0; i < 32; ++i) U[slot][rsel][i] = make_float2(b[i].x * rin, b[i].y * rin);
    }
    // wave-local fence: U writes visible to this wave's later reads (DS pipe is
    // in-order per wave; fence stops compiler reordering). No cross-wave sharing.
    asm volatile("s_waitcnt lgkmcnt(0)" ::: "memory");
    __builtin_amdgcn_sched_barrier(0);

    // ---- spectral multiply: y = conj(P)x at pix ; y = P x at cpix (rank-16) ----
    for (int ph = 0; ph < 2; ++ph) {
        if (ph == 1 && self) break;
        int px = ph ? cpix : pix;
        float sgn = ph ? -1.f : 1.f;
        for (int bb = 0; bb < NB; ++bb) {
            long adr = ((long)(bb * NCH + lane)) * NPIX + px;
            float2 xr = XF[adr];
            int mmode = lane & 15;
            float2 c = make_float2(0.f, 0.f);
            #pragma unroll
            for (int i = 0; i < 32; ++i) {
                float xx = __shfl(xr.x, sbase + i, 64);
                float xy = __shfl(xr.y, sbase + i, 64);
                float2 ul = U[slot][mmode][i];
                float uy = sgn * ul.y;
                c.x = fmaf(ul.x, xx, fmaf(-uy, xy, c.x));
                c.y = fmaf(ul.x, xy, fmaf( uy, xx, c.y));
            }
            float2 y = make_float2(0.f, 0.f);
            #pragma unroll
            for (int mm = 0; mm < 16; ++mm) {
                float cx = __shfl(c.x, sbase + mm, 64);
                float cy = __shfl(c.y, sbase + mm, 64);
                float2 ul = U[slot][mm][lane];
                float uy = sgn * ul.y;
                y.x = fmaf(ul.x, cx, fmaf( uy, cy, y.x));
                y.y = fmaf(ul.x, cy, fmaf(-uy, cx, y.y));
            }
            if (active) XF[adr] = y;
        }
    }

    // ---- dist: ||K-P||^2 = ||K||^2 - 2 Re tr(K^H P) + 16 ----
    build_kcol(ker, h, w, lane, b);   // rebuild original K column
    float kn = 0.f;
    #pragma unroll
    for (int i = 0; i < 32; ++i) kn = fmaf(b[i].x, b[i].x, fmaf(b[i].y, b[i].y, kn));
    float knt = halfsum(kn);
    float tr = 0.f;
    #pragma unroll
    for (int m = 0; m < 16; ++m) {
        float2 acc = make_float2(0.f, 0.f);
        #pragma unroll
        for (int rr = 0; rr < 32; ++rr) {
            float2 um = U[slot][m][rr];            // broadcast read
            acc.x = fmaf(b[rr].x, um.x, fmaf( b[rr].y, um.y, acc.x));  // conj(K_col).u_m
            acc.y = fmaf(b[rr].x, um.y, fmaf(-b[rr].y, um.x, acc.y));
        }
        float2 w0 = U[slot][m][lane];
        tr += w0.x * acc.x + w0.y * acc.y;          // Re(conj(u_om) * acc_o)
    }
    float trt = halfsum(tr);
    if (active && lane == 0) {
        float d2 = knt - 2.f * trt + 16.f;
        distP[gp] = (self ? 1.f : 2.f) * d2;
    }

    // ---- bias correction at DC pixel (gp==8064 -> (h,w)=(0,0)) ----
    if (active && gp == 8064) {
        int mmode = lane & 15;
        float2 d = make_float2(0.f, 0.f);
        #pragma unroll
        for (int i = 0; i < 32; ++i) {
            float bv = bias[i];
            float2 ul = U[slot][mmode][i];
            d.x = fmaf(ul.x, bv, d.x);
            d.y = fmaf(-ul.y, bv, d.y);             // conj(u) * bias
        }
        float racc = 0.f;
        #pragma unroll
        for (int mm = 0; mm < 16; ++mm) {
            float dx = __shfl(d.x, sbase + mm, 64);
            float dy = __shfl(d.y, sbase + mm, 64);
            float2 ul = U[slot][mm][lane];
            racc = fmaf(ul.x, dx, fmaf(-ul.y, dy, racc));   // Re(u * d)
        }
        biasp[lane] = bias[lane] - racc;
    }
}

__global__ __launch_bounds__(256) void k_inv_rows_bias(const float2* __restrict__ XF,
                                                       const float* __restrict__ biasp,
                                                       float* __restrict__ out) {
    __shared__ float2 buf[4][HW];
    int wave = threadIdx.x >> 6, lane = threadIdx.x & 63;
    long row = (long)blockIdx.x * 4 + wave;     // (b,o,h)
    int o = (int)((row >> 7) & 31);
    float bp = biasp[o];
    long base = row * HW;
    float2* d = buf[wave];
    d[lane]      = XF[base + lane];
    d[lane + 64] = XF[base + lane + 64];
    __syncthreads();
    fft128(d, lane, +1.f);
    const float sc = 1.0f / 128.0f;
    out[base + lane]      = d[lane].x * sc + bp;
    out[base + lane + 64] = d[lane + 64].x * sc + bp;
}

__global__ __launch_bounds__(256) void k_dist(const float* __restrict__ distP,
                                              float* __restrict__ out) {
    __shared__ float sh[256];
    float acc = 0.f;
    for (int i = threadIdx.x; i < NPROB; i += 256) acc += distP[i];
    sh[threadIdx.x] = acc;
    __syncthreads();
    for (int s = 128; s >= 1; s >>= 1) {
        if (threadIdx.x < s) sh[threadIdx.x] += sh[threadIdx.x + s];
        __syncthreads();
    }
    if (threadIdx.x == 0) out[(size_t)NB * NCH * NPIX] = sqrtf(sh[0]);
}

extern "C" void kernel_launch(void* const* d_in, const int* in_sizes, int n_in,
                              void* d_out, int out_size, void* d_ws, size_t ws_size,
                              hipStream_t stream) {
    (void)in_sizes; (void)n_in; (void)out_size; (void)ws_size;
    const float* x    = (const float*)d_in[0];
    const float* ker  = (const float*)d_in[1];
    const float* bias = (const float*)d_in[2];
    float* out = (float*)d_out;

    // ws: XF complex [16][32][128][128] (64 MiB) | distP [8194] | biasp [32]
    float2* XF   = (float2*)d_ws;
    float* distP = (float*)((char*)d_ws + (size_t)NB * NCH * NPIX * sizeof(float2));
    float* biasp = distP + NPROB;

    int rows = NB * NCH * HW;   // 65536
    k_fwd_rows<<<dim3(rows / 4), dim3(256), 0, stream>>>(x, XF);
    k_cols<<<dim3(NB * NCH * 8), dim3(256), 0, stream>>>(XF, -1.f);
    k_eig_apply3<<<dim3(1025), dim3(256), 0, stream>>>(ker, bias, XF, distP, biasp);
    k_cols<<<dim3(NB * NCH * 8), dim3(256), 0, stream>>>(XF, +1.f);
    k_inv_rows_bias<<<dim3(rows / 4), dim3(256), 0, stream>>>(XF, biasp, out);
    k_dist<<<dim3(1), dim3(256), 0, stream>>>(distP, out);
}

// Round 5
// 1849.698 us; speedup vs baseline: 1.4422x; 1.0417x over previous
//
#include <hip/hip_runtime.h>
#include <math.h>

#define NCH 32
#define NB  16
#define HW  128
#define NPIX (HW*HW)
#define NPROB 8194
#define PI_F 3.14159265358979323846f

__device__ __forceinline__ float2 cmulf(float2 a, float2 b) {
    return make_float2(a.x*b.x - a.y*b.y, a.x*b.y + a.y*b.x);
}
__device__ __forceinline__ int rev7(int i) { return (int)(__brev((unsigned)i) >> 25); }
// HW trig: input in revolutions (angle/2pi). Exact for dyadic-rational inputs.
__device__ __forceinline__ float hw_sin(float rev) { return __builtin_amdgcn_sinf(rev); }
__device__ __forceinline__ float hw_cos(float rev) { return __builtin_amdgcn_cosf(rev); }

// 128-point radix-2 DIF FFT in LDS; 64 lanes cooperate on one transform.
__device__ void fft128(float2* d, int lane, float sign) {
    for (int span = 64; span >= 1; span >>= 1) {
        int k = lane & (span - 1);
        int base = ((lane & ~(span - 1)) << 1) | k;
        float2 a = d[base];
        float2 b = d[base + span];
        float2 su = make_float2(a.x + b.x, a.y + b.y);
        float2 df = make_float2(a.x - b.x, a.y - b.y);
        float rev = (float)k / (float)(2 * span);      // |ang| = 2*pi*rev
        float cw = hw_cos(rev);
        float sw = sign * hw_sin(rev);
        d[base] = su;
        d[base + span] = cmulf(df, make_float2(cw, sw));
        __syncthreads();
    }
    float2 v0 = d[rev7(lane)];
    float2 v1 = d[rev7(lane + 64)];
    __syncthreads();
    d[lane] = v0;
    d[lane + 64] = v1;
    __syncthreads();
}

__global__ __launch_bounds__(256) void k_fwd_rows(const float* __restrict__ x,
                                                  float2* __restrict__ XF) {
    __shared__ float2 buf[4][HW];
    int wave = threadIdx.x >> 6, lane = threadIdx.x & 63;
    long row = (long)blockIdx.x * 4 + wave;
    long base = row * HW;
    const float sc = 1.0f / 128.0f;
    float2* d = buf[wave];
    d[lane]      = make_float2(x[base + lane] * sc, 0.f);
    d[lane + 64] = make_float2(x[base + lane + 64] * sc, 0.f);
    __syncthreads();
    fft128(d, lane, -1.f);
    XF[base + lane]      = d[lane];
    XF[base + lane + 64] = d[lane + 64];
}

__global__ __launch_bounds__(256) void k_cols(float2* __restrict__ XF, float sign) {
    __shared__ float2 tile[HW][17];
    int img = blockIdx.x >> 3;
    int w0  = (blockIdx.x & 7) << 4;
    long base = (long)img * NPIX + w0;
    int tid = threadIdx.x;
    for (int it = 0; it < 8; ++it) {
        int flat = it * 256 + tid;
        int h = flat >> 4, c = flat & 15;
        tile[h][c] = XF[base + (long)h * HW + c];
    }
    __syncthreads();
    for (int span = 64; span >= 1; span >>= 1) {
        for (int it = 0; it < 4; ++it) {
            int idx = it * 256 + tid;
            int j = idx >> 4, c = idx & 15;
            int k = j & (span - 1);
            int bidx = ((j & ~(span - 1)) << 1) | k;
            float2 a = tile[bidx][c], b = tile[bidx + span][c];
            float2 su = make_float2(a.x + b.x, a.y + b.y);
            float2 df = make_float2(a.x - b.x, a.y - b.y);
            float rev = (float)k / (float)(2 * span);
            float cw = hw_cos(rev);
            float sw = sign * hw_sin(rev);
            tile[bidx][c] = su;
            tile[bidx + span][c] = cmulf(df, make_float2(cw, sw));
        }
        __syncthreads();
    }
    float2 v[8];
    for (int it = 0; it < 8; ++it) {
        int flat = it * 256 + tid;
        int h = flat >> 4, c = flat & 15;
        v[it] = tile[rev7(h)][c];
    }
    __syncthreads();
    for (int it = 0; it < 8; ++it) {
        int flat = it * 256 + tid;
        int h = flat >> 4, c = flat & 15;
        tile[h][c] = v[it];
    }
    __syncthreads();
    for (int it = 0; it < 8; ++it) {
        int flat = it * 256 + tid;
        int h = flat >> 4, c = flat & 15;
        XF[base + (long)h * HW + c] = tile[h][c];
    }
}

__device__ __forceinline__ void prob_to_hw(int gp, int& h, int& w) {
    if (gp < 8064)      { h = 1 + (gp >> 7); w = gp & 127; }
    else if (gp < 8129) { h = 0;  w = gp - 8064; }
    else                { h = 64; w = gp - 8129; }
}

// build rows [rh*16, rh*16+16) of K column `col`: b[j] = K_{rh*16+j, col}(h,w)
__device__ __forceinline__ void build_kcol_half(const float* __restrict__ ker,
                                                int h, int w, int col, int rh, float2* b) {
    float twr[9], twi[9];
    #pragma unroll
    for (int u = 0; u < 3; ++u)
        #pragma unroll
        for (int v = 0; v < 3; ++v) {
            int idx = (h * u + w * v) & 127;
            float rev = (float)idx * (1.0f / 128.0f);
            twr[u * 3 + v] =  hw_cos(rev);
            twi[u * 3 + v] = -hw_sin(rev);
        }
    #pragma unroll
    for (int j = 0; j < 16; ++j) {
        int o = (rh << 4) + j;
        const float* kp = ker + (size_t)(o * NCH + col) * 9;
        float ar = 0.f, ai = 0.f;
        #pragma unroll
        for (int t = 0; t < 9; ++t) { float kv = kp[t]; ar = fmaf(kv, twr[t], ar); ai = fmaf(kv, twi[t], ai); }
        b[j] = make_float2(ar, ai);
    }
}

__device__ __forceinline__ float halfsum(float v) {
    v += __shfl_xor(v, 1);  v += __shfl_xor(v, 2);  v += __shfl_xor(v, 4);
    v += __shfl_xor(v, 8);  v += __shfl_xor(v, 16);
    return v;
}
__device__ __forceinline__ float wsum64(float v) {
    v = halfsum(v); v += __shfl_xor(v, 32);
    return v;
}

// One-sided Jacobi SVD per pixel. 64 lanes per problem: lane (rh,col) owns
// rows [rh*16, rh*16+16) of column col -> b[16] (32 VGPR, no spill).
// 4 problems per 256-thread block; waves fully independent (no __syncthreads).
__global__ void k_eig_apply4(
    const float* __restrict__ ker, const float* __restrict__ bias,
    float2* __restrict__ XF, float* __restrict__ distP, float* __restrict__ biasp)
{
    __shared__ float2 U[4][16][33];   // per-wave slice: U[wv][m][i] = u_{i,m}

    int tid  = threadIdx.x;
    int wv   = tid >> 6;              // wave id = problem slot
    int l64  = tid & 63;
    int rh   = l64 >> 5;              // row half
    int col  = l64 & 31;              // column owned
    int sbase = rh << 5;

    int gp = blockIdx.x * 4 + wv;
    bool active = gp < NPROB;
    int gpe = active ? gp : 0;
    int h, w; prob_to_hw(gpe, h, w);
    int pix = (h << 7) | w;
    int hc = (128 - h) & 127, wc = (128 - w) & 127;
    int cpix = (hc << 7) | wc;
    bool self = (cpix == pix);

    float2 b[16];
    build_kcol_half(ker, h, w, col, rh, b);

    // ---- one-sided Jacobi, XOR-pair ordering over columns ----
    for (int sweep = 0; sweep < 8; ++sweep) {
        float offacc = 0.f;
        for (int m = 1; m < 32; ++m) {
            bool isP = col < (col ^ m);
            // partial 2x2 Gram over own 16 rows; symmetric accumulators ->
            // all 4 lanes of a pair-group get bitwise-identical values.
            float no = 0.f, gre = 0.f, A = 0.f, Bm = 0.f;
            #pragma unroll
            for (int i = 0; i < 16; ++i) {
                float fx = __shfl_xor(b[i].x, m, 64);
                float fy = __shfl_xor(b[i].y, m, 64);
                no  = fmaf(b[i].x, b[i].x, fmaf(b[i].y, b[i].y, no));
                gre = fmaf(b[i].x, fx, fmaf(b[i].y, fy, gre));
                A   = fmaf(b[i].x, fy, A);
                Bm  = fmaf(b[i].y, fx, Bm);
            }
            // cross-half row reduction (commutative adds keep bit-identity)
            no  += __shfl_xor(no,  32, 64);
            gre += __shfl_xor(gre, 32, 64);
            A   += __shfl_xor(A,   32, 64);
            Bm  += __shfl_xor(Bm,  32, 64);
            float nf  = __shfl_xor(no, m, 64);
            float app = isP ? no : nf;
            float aqq = isP ? nf : no;
            float gim = isP ? (A - Bm) : (Bm - A);
            float n2 = gre * gre + gim * gim;
            offacc += n2;

            bool doRot = (n2 > 1e-24f * app * aqq) && (n2 > 1e-36f);
            if (__ballot(doRot)) {
                float ad  = sqrtf(n2);
                float tau = (aqq - app) / (2.f * ad);
                float tt  = (tau >= 0.f ? 1.f : -1.f) / (fabsf(tau) + sqrtf(fmaf(tau, tau, 1.f)));
                float cc  = rsqrtf(fmaf(tt, tt, 1.f));
                float sg  = tt * cc / ad;
                float ssx = sg * gre, ssy = sg * gim;
                float gx  = isP ? -ssx : ssx;   // p: -conj(s), q: +s
                float gy  = ssy;
                if (!doRot) { cc = 1.f; gx = 0.f; gy = 0.f; }
                #pragma unroll
                for (int i = 0; i < 16; ++i) {
                    float fx = __shfl_xor(b[i].x, m, 64);
                    float fy = __shfl_xor(b[i].y, m, 64);
                    b[i].x = fmaf(cc, b[i].x, fmaf(gx, fx, -gy * fy));
                    b[i].y = fmaf(cc, b[i].y, fmaf(gx, fy,  gy * fx));
                }
            }
        }
        // convergence: 2*sum|g|^2 <= 1e-12 * sum(sigma^4)
        float nr = 0.f;
        #pragma unroll
        for (int i = 0; i < 16; ++i) nr = fmaf(b[i].x, b[i].x, fmaf(b[i].y, b[i].y, nr));
        float nrF  = nr + __shfl_xor(nr, 32, 64);     // full column norm^2
        float dg   = halfsum(nrF * nrF);
        float offT = halfsum(offacc);
        if (!__ballot(offT > 1e-12f * dg)) break;
    }

    // ---- top-16 selection by column norm, compact (normalized) into LDS ----
    float nr = 0.f;
    #pragma unroll
    for (int i = 0; i < 16; ++i) nr = fmaf(b[i].x, b[i].x, fmaf(b[i].y, b[i].y, nr));
    float nrF = nr + __shfl_xor(nr, 32, 64);
    int rank = 0;
    #pragma unroll
    for (int k = 0; k < 32; ++k) {
        float nk = __shfl(nrF, k, 64);     // nrF identical across rh halves
        if (nk > nrF || (nk == nrF && k < col)) ++rank;
    }
    bool sel = rank < 16;
    unsigned long long ball = __ballot(sel);
    unsigned cmask = (unsigned)(ball & 0xFFFFFFFFull);
    int rsel = __popc(cmask & ((1u << col) - 1u));
    float rin = rsqrtf(fmaxf(nrF, 1e-30f));
    if (sel) {
        #pragma unroll
        for (int j = 0; j < 16; ++j)
            U[wv][rsel][(rh << 4) + j] = make_float2(b[j].x * rin, b[j].y * rin);
    }
    // wave-local fence (DS in-order per wave; stops compiler reordering).
    asm volatile("s_waitcnt lgkmcnt(0)" ::: "memory");
    __builtin_amdgcn_sched_barrier(0);

    // ---- spectral multiply: y = conj(P)x at pix ; y = P x at cpix (rank-16) ----
    // rh halves split the batch dimension: bbi = 2*b2 + rh.
    for (int ph = 0; ph < 2; ++ph) {
        if (ph == 1 && self) break;
        int px = ph ? cpix : pix;
        float sgn = ph ? -1.f : 1.f;
        for (int b2 = 0; b2 < 8; ++b2) {
            int bbi = (b2 << 1) | rh;
            long adr = ((long)(bbi * NCH + col)) * NPIX + px;
            float2 xr = XF[adr];
            int mmode = col & 15;
            float2 c = make_float2(0.f, 0.f);
            #pragma unroll
            for (int i = 0; i < 32; ++i) {
                float xx = __shfl(xr.x, sbase + i, 64);
                float xy = __shfl(xr.y, sbase + i, 64);
                float2 ul = U[wv][mmode][i];
                float uy = sgn * ul.y;
                c.x = fmaf(ul.x, xx, fmaf(-uy, xy, c.x));
                c.y = fmaf(ul.x, xy, fmaf( uy, xx, c.y));
            }
            float2 y = make_float2(0.f, 0.f);
            #pragma unroll
            for (int mm = 0; mm < 16; ++mm) {
                float cx = __shfl(c.x, sbase + mm, 64);
                float cy = __shfl(c.y, sbase + mm, 64);
                float2 ul = U[wv][mm][col];
                float uy = sgn * ul.y;
                y.x = fmaf(ul.x, cx, fmaf( uy, cy, y.x));
                y.y = fmaf(ul.x, cy, fmaf(-uy, cx, y.y));
            }
            if (active) XF[adr] = y;
        }
    }

    // ---- dist: ||K-P||^2 = ||K||^2 - 2 Re tr(K^H P) + 16 ----
    build_kcol_half(ker, h, w, col, rh, b);   // rebuild original K rows
    float kn = 0.f;
    #pragma unroll
    for (int j = 0; j < 16; ++j) kn = fmaf(b[j].x, b[j].x, fmaf(b[j].y, b[j].y, kn));
    float knt = wsum64(kn);
    float tr = 0.f;                            // counted by BOTH rh halves -> 2x
    #pragma unroll
    for (int m = 0; m < 16; ++m) {
        float2 acc = make_float2(0.f, 0.f);
        #pragma unroll
        for (int j = 0; j < 16; ++j) {
            float2 um = U[wv][m][(rh << 4) + j];
            acc.x = fmaf(b[j].x, um.x, fmaf( b[j].y, um.y, acc.x));   // <k_col, u_m>
            acc.y = fmaf(b[j].x, um.y, fmaf(-b[j].y, um.x, acc.y));
        }
        acc.x += __shfl_xor(acc.x, 32, 64);
        acc.y += __shfl_xor(acc.y, 32, 64);
        float2 w0 = U[wv][m][col];
        tr = fmaf(w0.x, acc.x, fmaf(w0.y, acc.y, tr));
    }
    float trt = wsum64(tr);                    // = 2 * Re tr(K^H P)
    if (active && l64 == 0) {
        float d2 = knt - trt + 16.f;
        distP[gp] = (self ? 1.f : 2.f) * d2;
    }

    // ---- bias correction at DC pixel (gp==8064 -> (h,w)=(0,0)) ----
    if (active && gp == 8064) {
        int mmode = col & 15;
        float2 d = make_float2(0.f, 0.f);
        #pragma unroll
        for (int j = 0; j < 16; ++j) {
            int i = (rh << 4) + j;
            float bv = bias[i];
            float2 ul = U[wv][mmode][i];
            d.x = fmaf(ul.x, bv, d.x);
            d.y = fmaf(-ul.y, bv, d.y);        // conj(u) * bias
        }
        d.x += __shfl_xor(d.x, 32, 64);
        d.y += __shfl_xor(d.y, 32, 64);
        float racc = 0.f;
        #pragma unroll
        for (int mm = 0; mm < 16; ++mm) {
            float dx = __shfl(d.x, sbase + mm, 64);
            float dy = __shfl(d.y, sbase + mm, 64);
            float2 ul = U[wv][mm][col];
            racc = fmaf(ul.x, dx, fmaf(-ul.y, dy, racc));   // Re(u * d)
        }
        if (rh == 0) biasp[col] = bias[col] - racc;
    }
}

__global__ __launch_bounds__(256) void k_inv_rows_bias(const float2* __restrict__ XF,
                                                       const float* __restrict__ biasp,
                                                       float* __restrict__ out) {
    __shared__ float2 buf[4][HW];
    int wave = threadIdx.x >> 6, lane = threadIdx.x & 63;
    long row = (long)blockIdx.x * 4 + wave;     // (b,o,h)
    int o = (int)((row >> 7) & 31);
    float bp = biasp[o];
    long base = row * HW;
    float2* d = buf[wave];
    d[lane]      = XF[base + lane];
    d[lane + 64] = XF[base + lane + 64];
    __syncthreads();
    fft128(d, lane, +1.f);
    const float sc = 1.0f / 128.0f;
    out[base + lane]      = d[lane].x * sc + bp;
    out[base + lane + 64] = d[lane + 64].x * sc + bp;
}

__global__ __launch_bounds__(256) void k_dist(const float* __restrict__ distP,
                                              float* __restrict__ out) {
    __shared__ float sh[256];
    float acc = 0.f;
    for (int i = threadIdx.x; i < NPROB; i += 256) acc += distP[i];
    sh[threadIdx.x] = acc;
    __syncthreads();
    for (int s = 128; s >= 1; s >>= 1) {
        if (threadIdx.x < s) sh[threadIdx.x] += sh[threadIdx.x + s];
        __syncthreads();
    }
    if (threadIdx.x == 0) out[(size_t)NB * NCH * NPIX] = sqrtf(sh[0]);
}

extern "C" void kernel_launch(void* const* d_in, const int* in_sizes, int n_in,
                              void* d_out, int out_size, void* d_ws, size_t ws_size,
                              hipStream_t stream) {
    (void)in_sizes; (void)n_in; (void)out_size; (void)ws_size;
    const float* x    = (const float*)d_in[0];
    const float* ker  = (const float*)d_in[1];
    const float* bias = (const float*)d_in[2];
    float* out = (float*)d_out;

    // ws: XF complex [16][32][128][128] (64 MiB) | distP [8194] | biasp [32]
    float2* XF   = (float2*)d_ws;
    float* distP = (float*)((char*)d_ws + (size_t)NB * NCH * NPIX * sizeof(float2));
    float* biasp = distP + NPROB;

    int rows = NB * NCH * HW;   // 65536
    k_fwd_rows<<<dim3(rows / 4), dim3(256), 0, stream>>>(x, XF);
    k_cols<<<dim3(NB * NCH * 8), dim3(256), 0, stream>>>(XF, -1.f);
    k_eig_apply4<<<dim3((NPROB + 3) / 4), dim3(256), 0, stream>>>(ker, bias, XF, distP, biasp);
    k_cols<<<dim3(NB * NCH * 8), dim3(256), 0, stream>>>(XF, +1.f);
    k_inv_rows_bias<<<dim3(rows / 4), dim3(256), 0, stream>>>(XF, biasp, out);
    k_dist<<<dim3(1), dim3(256), 0, stream>>>(distP, out);
}

// Round 6
// 1715.501 us; speedup vs baseline: 1.5550x; 1.0782x over previous
//
#include <hip/hip_runtime.h>
#include <math.h>

#define NCH 32
#define NB  16
#define HW  128
#define NPIX (HW*HW)
#define NPROB 8194

__device__ __forceinline__ float2 cmulf(float2 a, float2 b) {
    return make_float2(a.x*b.x - a.y*b.y, a.x*b.y + a.y*b.x);
}
__device__ __forceinline__ int rev7(int i) { return (int)(__brev((unsigned)i) >> 25); }
// HW trig: input in revolutions (angle/2pi). Exact for dyadic-rational inputs.
__device__ __forceinline__ float hw_sin(float rev) { return __builtin_amdgcn_sinf(rev); }
__device__ __forceinline__ float hw_cos(float rev) { return __builtin_amdgcn_cosf(rev); }

// 128-point radix-2 DIF FFT in LDS; 64 lanes cooperate on one transform.
__device__ void fft128(float2* d, int lane, float sign) {
    for (int span = 64; span >= 1; span >>= 1) {
        int k = lane & (span - 1);
        int base = ((lane & ~(span - 1)) << 1) | k;
        float2 a = d[base];
        float2 b = d[base + span];
        float2 su = make_float2(a.x + b.x, a.y + b.y);
        float2 df = make_float2(a.x - b.x, a.y - b.y);
        float rev = (float)k / (float)(2 * span);
        float cw = hw_cos(rev);
        float sw = sign * hw_sin(rev);
        d[base] = su;
        d[base + span] = cmulf(df, make_float2(cw, sw));
        __syncthreads();
    }
    float2 v0 = d[rev7(lane)];
    float2 v1 = d[rev7(lane + 64)];
    __syncthreads();
    d[lane] = v0;
    d[lane + 64] = v1;
    __syncthreads();
}

__global__ __launch_bounds__(256) void k_fwd_rows(const float* __restrict__ x,
                                                  float2* __restrict__ XF) {
    __shared__ float2 buf[4][HW];
    int wave = threadIdx.x >> 6, lane = threadIdx.x & 63;
    long row = (long)blockIdx.x * 4 + wave;
    long base = row * HW;
    const float sc = 1.0f / 128.0f;
    float2* d = buf[wave];
    d[lane]      = make_float2(x[base + lane] * sc, 0.f);
    d[lane + 64] = make_float2(x[base + lane + 64] * sc, 0.f);
    __syncthreads();
    fft128(d, lane, -1.f);
    XF[base + lane]      = d[lane];
    XF[base + lane + 64] = d[lane + 64];
}

__global__ __launch_bounds__(256) void k_cols(float2* __restrict__ XF, float sign) {
    __shared__ float2 tile[HW][17];
    int img = blockIdx.x >> 3;
    int w0  = (blockIdx.x & 7) << 4;
    long base = (long)img * NPIX + w0;
    int tid = threadIdx.x;
    for (int it = 0; it < 8; ++it) {
        int flat = it * 256 + tid;
        int h = flat >> 4, c = flat & 15;
        tile[h][c] = XF[base + (long)h * HW + c];
    }
    __syncthreads();
    for (int span = 64; span >= 1; span >>= 1) {
        for (int it = 0; it < 4; ++it) {
            int idx = it * 256 + tid;
            int j = idx >> 4, c = idx & 15;
            int k = j & (span - 1);
            int bidx = ((j & ~(span - 1)) << 1) | k;
            float2 a = tile[bidx][c], b = tile[bidx + span][c];
            float2 su = make_float2(a.x + b.x, a.y + b.y);
            float2 df = make_float2(a.x - b.x, a.y - b.y);
            float rev = (float)k / (float)(2 * span);
            float cw = hw_cos(rev);
            float sw = sign * hw_sin(rev);
            tile[bidx][c] = su;
            tile[bidx + span][c] = cmulf(df, make_float2(cw, sw));
        }
        __syncthreads();
    }
    float2 v[8];
    for (int it = 0; it < 8; ++it) {
        int flat = it * 256 + tid;
        int h = flat >> 4, c = flat & 15;
        v[it] = tile[rev7(h)][c];
    }
    __syncthreads();
    for (int it = 0; it < 8; ++it) {
        int flat = it * 256 + tid;
        int h = flat >> 4, c = flat & 15;
        tile[h][c] = v[it];
    }
    __syncthreads();
    for (int it = 0; it < 8; ++it) {
        int flat = it * 256 + tid;
        int h = flat >> 4, c = flat & 15;
        XF[base + (long)h * HW + c] = tile[h][c];
    }
}

__device__ __forceinline__ void prob_to_hw(int gp, int& h, int& w) {
    if (gp < 8064)      { h = 1 + (gp >> 7); w = gp & 127; }
    else if (gp < 8129) { h = 0;  w = gp - 8064; }
    else                { h = 64; w = gp - 8129; }
}

// pixel (h,w) -> (representative problem gp, conjugate flag)
__device__ __forceinline__ void pix_to_prob(int h, int w, int& gp, bool& cj) {
    if (h >= 1 && h <= 63)      { gp = (h - 1) * 128 + w; cj = false; }
    else if (h >= 65)           { gp = (127 - h) * 128 + ((128 - w) & 127); cj = true; }
    else if (h == 0)            { if (w <= 64) { gp = 8064 + w; cj = false; }
                                  else        { gp = 8064 + 128 - w; cj = true; } }
    else                        { if (w <= 64) { gp = 8129 + w; cj = false; }
                                  else        { gp = 8129 + 128 - w; cj = true; } }
}

// build rows [rh*16, rh*16+16) of K column `col`: b[j] = K_{rh*16+j, col}(h,w)
__device__ __forceinline__ void build_kcol_half(const float* __restrict__ ker,
                                                int h, int w, int col, int rh, float2* b) {
    float twr[9], twi[9];
    #pragma unroll
    for (int u = 0; u < 3; ++u)
        #pragma unroll
        for (int v = 0; v < 3; ++v) {
            int idx = (h * u + w * v) & 127;
            float rev = (float)idx * (1.0f / 128.0f);
            twr[u * 3 + v] =  hw_cos(rev);
            twi[u * 3 + v] = -hw_sin(rev);
        }
    #pragma unroll
    for (int j = 0; j < 16; ++j) {
        int o = (rh << 4) + j;
        const float* kp = ker + (size_t)(o * NCH + col) * 9;
        float ar = 0.f, ai = 0.f;
        #pragma unroll
        for (int t = 0; t < 9; ++t) { float kv = kp[t]; ar = fmaf(kv, twr[t], ar); ai = fmaf(kv, twi[t], ai); }
        b[j] = make_float2(ar, ai);
    }
}

__device__ __forceinline__ float halfsum(float v) {
    v += __shfl_xor(v, 1);  v += __shfl_xor(v, 2);  v += __shfl_xor(v, 4);
    v += __shfl_xor(v, 8);  v += __shfl_xor(v, 16);
    return v;
}
__device__ __forceinline__ float wsum64(float v) {
    v = halfsum(v); v += __shfl_xor(v, 32);
    return v;
}

// One-sided Jacobi SVD per pixel (eig only — no XF access). 64 lanes/problem:
// lane (rh,col) owns rows [rh*16,rh*16+16) of column col. 4 problems per block.
// Writes normalized top-16 columns to Uws[gp][m][i] (+ distP, biasp).
__global__ __launch_bounds__(256, 1) void k_eig(
    const float* __restrict__ ker, const float* __restrict__ bias,
    float2* __restrict__ Uws, float* __restrict__ distP, float* __restrict__ biasp)
{
    __shared__ float2 U[4][16][33];   // per-wave slice for dist/bias tail

    int tid  = threadIdx.x;
    int wv   = tid >> 6;
    int l64  = tid & 63;
    int rh   = l64 >> 5;
    int col  = l64 & 31;
    int sbase = rh << 5;

    int gp = blockIdx.x * 4 + wv;
    bool active = gp < NPROB;
    int gpe = active ? gp : 0;
    int h, w; prob_to_hw(gpe, h, w);
    int hc = (128 - h) & 127, wc = (128 - w) & 127;
    bool self = (hc == h && wc == w);

    float2 b[16];
    build_kcol_half(ker, h, w, col, rh, b);

    // ---- one-sided Jacobi, XOR-pair ordering over columns ----
    for (int sweep = 0; sweep < 8; ++sweep) {
        float offacc = 0.f;
        for (int m = 1; m < 32; ++m) {
            bool isP = col < (col ^ m);
            float no = 0.f, gre = 0.f, A = 0.f, Bm = 0.f;
            #pragma unroll
            for (int i = 0; i < 16; ++i) {
                float fx = __shfl_xor(b[i].x, m, 64);
                float fy = __shfl_xor(b[i].y, m, 64);
                no  = fmaf(b[i].x, b[i].x, fmaf(b[i].y, b[i].y, no));
                gre = fmaf(b[i].x, fx, fmaf(b[i].y, fy, gre));
                A   = fmaf(b[i].x, fy, A);
                Bm  = fmaf(b[i].y, fx, Bm);
            }
            no  += __shfl_xor(no,  32, 64);
            gre += __shfl_xor(gre, 32, 64);
            A   += __shfl_xor(A,   32, 64);
            Bm  += __shfl_xor(Bm,  32, 64);
            float nf  = __shfl_xor(no, m, 64);
            float app = isP ? no : nf;
            float aqq = isP ? nf : no;
            float gim = isP ? (A - Bm) : (Bm - A);
            float n2 = gre * gre + gim * gim;
            offacc += n2;

            bool doRot = (n2 > 1e-24f * app * aqq) && (n2 > 1e-36f);
            if (__ballot(doRot)) {
                float ad  = sqrtf(n2);
                float tau = (aqq - app) / (2.f * ad);
                float tt  = (tau >= 0.f ? 1.f : -1.f) / (fabsf(tau) + sqrtf(fmaf(tau, tau, 1.f)));
                float cc  = rsqrtf(fmaf(tt, tt, 1.f));
                float sg  = tt * cc / ad;
                float ssx = sg * gre, ssy = sg * gim;
                float gx  = isP ? -ssx : ssx;
                float gy  = ssy;
                if (!doRot) { cc = 1.f; gx = 0.f; gy = 0.f; }
                #pragma unroll
                for (int i = 0; i < 16; ++i) {
                    float fx = __shfl_xor(b[i].x, m, 64);
                    float fy = __shfl_xor(b[i].y, m, 64);
                    b[i].x = fmaf(cc, b[i].x, fmaf(gx, fx, -gy * fy));
                    b[i].y = fmaf(cc, b[i].y, fmaf(gx, fy,  gy * fx));
                }
            }
        }
        float nr = 0.f;
        #pragma unroll
        for (int i = 0; i < 16; ++i) nr = fmaf(b[i].x, b[i].x, fmaf(b[i].y, b[i].y, nr));
        float nrF  = nr + __shfl_xor(nr, 32, 64);
        float dg   = halfsum(nrF * nrF);
        float offT = halfsum(offacc);
        if (!__ballot(offT > 1e-12f * dg)) break;
    }

    // ---- top-16 selection by column norm; write normalized U to LDS + global ----
    float nr = 0.f;
    #pragma unroll
    for (int i = 0; i < 16; ++i) nr = fmaf(b[i].x, b[i].x, fmaf(b[i].y, b[i].y, nr));
    float nrF = nr + __shfl_xor(nr, 32, 64);
    int rank = 0;
    #pragma unroll
    for (int k = 0; k < 32; ++k) {
        float nk = __shfl(nrF, k, 64);
        if (nk > nrF || (nk == nrF && k < col)) ++rank;
    }
    bool sel = rank < 16;
    unsigned long long ball = __ballot(sel);
    unsigned cmask = (unsigned)(ball & 0xFFFFFFFFull);
    int rsel = __popc(cmask & ((1u << col) - 1u));
    float rin = rsqrtf(fmaxf(nrF, 1e-30f));
    if (sel) {
        #pragma unroll
        for (int j = 0; j < 16; ++j) {
            float2 uv = make_float2(b[j].x * rin, b[j].y * rin);
            U[wv][rsel][(rh << 4) + j] = uv;
            if (active) Uws[((size_t)gp * 16 + rsel) * 32 + (rh << 4) + j] = uv;
        }
    }
    asm volatile("s_waitcnt lgkmcnt(0)" ::: "memory");
    __builtin_amdgcn_sched_barrier(0);

    // ---- dist: ||K-P||^2 = ||K||^2 - 2 Re tr(K^H P) + 16 ----
    build_kcol_half(ker, h, w, col, rh, b);
    float kn = 0.f;
    #pragma unroll
    for (int j = 0; j < 16; ++j) kn = fmaf(b[j].x, b[j].x, fmaf(b[j].y, b[j].y, kn));
    float knt = wsum64(kn);
    float tr = 0.f;                            // both rh halves count -> 2x
    #pragma unroll
    for (int m = 0; m < 16; ++m) {
        float2 acc = make_float2(0.f, 0.f);
        #pragma unroll
        for (int j = 0; j < 16; ++j) {
            float2 um = U[wv][m][(rh << 4) + j];
            acc.x = fmaf(b[j].x, um.x, fmaf( b[j].y, um.y, acc.x));
            acc.y = fmaf(b[j].x, um.y, fmaf(-b[j].y, um.x, acc.y));
        }
        acc.x += __shfl_xor(acc.x, 32, 64);
        acc.y += __shfl_xor(acc.y, 32, 64);
        float2 w0 = U[wv][m][col];
        tr = fmaf(w0.x, acc.x, fmaf(w0.y, acc.y, tr));
    }
    float trt = wsum64(tr);                    // = 2 * Re tr(K^H P)
    if (active && l64 == 0) {
        float d2 = knt - trt + 16.f;
        distP[gp] = (self ? 1.f : 2.f) * d2;
    }

    // ---- bias correction at DC pixel (gp==8064 -> (h,w)=(0,0)) ----
    if (active && gp == 8064) {
        int mmode = col & 15;
        float2 d = make_float2(0.f, 0.f);
        #pragma unroll
        for (int j = 0; j < 16; ++j) {
            int i = (rh << 4) + j;
            float bv = bias[i];
            float2 ul = U[wv][mmode][i];
            d.x = fmaf(ul.x, bv, d.x);
            d.y = fmaf(-ul.y, bv, d.y);
        }
        d.x += __shfl_xor(d.x, 32, 64);
        d.y += __shfl_xor(d.y, 32, 64);
        float racc = 0.f;
        #pragma unroll
        for (int mm = 0; mm < 16; ++mm) {
            float dx = __shfl(d.x, sbase + mm, 64);
            float dy = __shfl(d.y, sbase + mm, 64);
            float2 ul = U[wv][mm][col];
            racc = fmaf(ul.x, dx, fmaf(-ul.y, dy, racc));
        }
        if (rh == 0) biasp[col] = bias[col] - racc;
    }
}

// Apply y_f = conj(P) x_f per pixel, rank-16 form. 8 consecutive pixels per
// block (one 64B line per (b,c) row -> coalesced). U staged in LDS.
// direct: y = conj(U)(U^T x); conj-pixel: y = U (U^H x).
__global__ __launch_bounds__(256) void k_apply(const float2* __restrict__ Uws,
                                               float2* __restrict__ XF)
{
    __shared__ float2 Us[16][33][9];   // [m][i][slot] (pads kill 8-way conflicts)
    __shared__ float2 xs[32][9];       // [c][slot]
    __shared__ float2 ts[16][9];       // [m][slot]

    int tid = threadIdx.x;
    int pb = blockIdx.x * 8;
    int h = pb >> 7, w0 = pb & 127;

    // --- stage U for the 8 pixels of this block ---
    {
        int slot = tid >> 5, t5 = tid & 31;
        int gp; bool cj;
        pix_to_prob(h, w0 + slot, gp, cj);
        size_t gbase = (size_t)gp * 512 + (size_t)t5 * 16;
        #pragma unroll
        for (int j = 0; j < 16; ++j) {
            int e = t5 * 16 + j;
            Us[e >> 5][e & 31][slot] = Uws[gbase + j];
        }
    }
    __syncthreads();

    int c = tid >> 3, ws = tid & 7;
    int gp; bool cj;
    pix_to_prob(h, w0 + ws, gp, cj);
    float sgn = cj ? -1.f : 1.f;
    long pbase = (long)h * 128 + (w0 + ws);

    for (int bb = 0; bb < NB; ++bb) {
        long adr = ((long)(bb * NCH + c)) * NPIX + pbase;
        xs[c][ws] = XF[adr];
        __syncthreads();
        if (c < 16) {
            float2 t = make_float2(0.f, 0.f);
            #pragma unroll
            for (int i = 0; i < 32; ++i) {
                float2 ul = Us[c][i][ws];
                float uy = sgn * ul.y;
                float2 xr = xs[i][ws];
                t.x = fmaf(ul.x, xr.x, fmaf(-uy, xr.y, t.x));
                t.y = fmaf(ul.x, xr.y, fmaf( uy, xr.x, t.y));
            }
            ts[c][ws] = t;
        }
        __syncthreads();
        float2 y = make_float2(0.f, 0.f);
        #pragma unroll
        for (int m = 0; m < 16; ++m) {
            float2 ul = Us[m][c][ws];
            float uy = sgn * ul.y;
            float2 t = ts[m][ws];
            y.x = fmaf(ul.x, t.x, fmaf( uy, t.y, y.x));
            y.y = fmaf(ul.x, t.y, fmaf(-uy, t.x, y.y));
        }
        XF[adr] = y;
        __syncthreads();
    }
}

__global__ __launch_bounds__(256) void k_inv_rows_bias(const float2* __restrict__ XF,
                                                       const float* __restrict__ biasp,
                                                       float* __restrict__ out) {
    __shared__ float2 buf[4][HW];
    int wave = threadIdx.x >> 6, lane = threadIdx.x & 63;
    long row = (long)blockIdx.x * 4 + wave;     // (b,o,h)
    int o = (int)((row >> 7) & 31);
    float bp = biasp[o];
    long base = row * HW;
    float2* d = buf[wave];
    d[lane]      = XF[base + lane];
    d[lane + 64] = XF[base + lane + 64];
    __syncthreads();
    fft128(d, lane, +1.f);
    const float sc = 1.0f / 128.0f;
    out[base + lane]      = d[lane].x * sc + bp;
    out[base + lane + 64] = d[lane + 64].x * sc + bp;
}

__global__ __launch_bounds__(256) void k_dist(const float* __restrict__ distP,
                                              float* __restrict__ out) {
    __shared__ float sh[256];
    float acc = 0.f;
    for (int i = threadIdx.x; i < NPROB; i += 256) acc += distP[i];
    sh[threadIdx.x] = acc;
    __syncthreads();
    for (int s = 128; s >= 1; s >>= 1) {
        if (threadIdx.x < s) sh[threadIdx.x] += sh[threadIdx.x + s];
        __syncthreads();
    }
    if (threadIdx.x == 0) out[(size_t)NB * NCH * NPIX] = sqrtf(sh[0]);
}

extern "C" void kernel_launch(void* const* d_in, const int* in_sizes, int n_in,
                              void* d_out, int out_size, void* d_ws, size_t ws_size,
                              hipStream_t stream) {
    (void)in_sizes; (void)n_in; (void)out_size; (void)ws_size;
    const float* x    = (const float*)d_in[0];
    const float* ker  = (const float*)d_in[1];
    const float* bias = (const float*)d_in[2];
    float* out = (float*)d_out;

    // ws: XF complex [16][32][128][128] (64 MiB) | distP [8194] | biasp [32]
    float2* XF   = (float2*)d_ws;
    float* distP = (float*)((char*)d_ws + (size_t)NB * NCH * NPIX * sizeof(float2));
    float* biasp = distP + NPROB;
    // U scratch in the tail of d_out (33.6 MB at +96 MB; overwritten later by
    // k_inv_rows_bias, which runs after k_apply has consumed it — stream order).
    float2* Uws = (float2*)((char*)d_out + ((size_t)96 << 20));

    int rows = NB * NCH * HW;   // 65536
    k_fwd_rows<<<dim3(rows / 4), dim3(256), 0, stream>>>(x, XF);
    k_cols<<<dim3(NB * NCH * 8), dim3(256), 0, stream>>>(XF, -1.f);
    k_eig<<<dim3((NPROB + 3) / 4), dim3(256), 0, stream>>>(ker, bias, Uws, distP, biasp);
    k_apply<<<dim3(NPIX / 8), dim3(256), 0, stream>>>(Uws, XF);
    k_cols<<<dim3(NB * NCH * 8), dim3(256), 0, stream>>>(XF, +1.f);
    k_inv_rows_bias<<<dim3(rows / 4), dim3(256), 0, stream>>>(XF, biasp, out);
    k_dist<<<dim3(1), dim3(256), 0, stream>>>(distP, out);
}

// Round 7
// 1127.638 us; speedup vs baseline: 2.3657x; 1.5213x over previous
//
#include <hip/hip_runtime.h>
#include <math.h>

#define NCH 32
#define NB  16
#define HW  128
#define NPIX (HW*HW)
#define NPROB 8194

__device__ __forceinline__ float2 cmulf(float2 a, float2 b) {
    return make_float2(a.x*b.x - a.y*b.y, a.x*b.y + a.y*b.x);
}
__device__ __forceinline__ int rev7(int i) { return (int)(__brev((unsigned)i) >> 25); }
// HW trig: input in revolutions (angle/2pi). Exact for dyadic-rational inputs.
__device__ __forceinline__ float hw_sin(float rev) { return __builtin_amdgcn_sinf(rev); }
__device__ __forceinline__ float hw_cos(float rev) { return __builtin_amdgcn_cosf(rev); }

// 128-point radix-2 DIF FFT in LDS; 64 lanes cooperate on one transform.
__device__ void fft128(float2* d, int lane, float sign) {
    for (int span = 64; span >= 1; span >>= 1) {
        int k = lane & (span - 1);
        int base = ((lane & ~(span - 1)) << 1) | k;
        float2 a = d[base];
        float2 b = d[base + span];
        float2 su = make_float2(a.x + b.x, a.y + b.y);
        float2 df = make_float2(a.x - b.x, a.y - b.y);
        float rev = (float)k / (float)(2 * span);
        float cw = hw_cos(rev);
        float sw = sign * hw_sin(rev);
        d[base] = su;
        d[base + span] = cmulf(df, make_float2(cw, sw));
        __syncthreads();
    }
    float2 v0 = d[rev7(lane)];
    float2 v1 = d[rev7(lane + 64)];
    __syncthreads();
    d[lane] = v0;
    d[lane + 64] = v1;
    __syncthreads();
}

__global__ __launch_bounds__(256) void k_fwd_rows(const float* __restrict__ x,
                                                  float2* __restrict__ XF) {
    __shared__ float2 buf[4][HW];
    int wave = threadIdx.x >> 6, lane = threadIdx.x & 63;
    long row = (long)blockIdx.x * 4 + wave;
    long base = row * HW;
    const float sc = 1.0f / 128.0f;
    float2* d = buf[wave];
    d[lane]      = make_float2(x[base + lane] * sc, 0.f);
    d[lane + 64] = make_float2(x[base + lane + 64] * sc, 0.f);
    __syncthreads();
    fft128(d, lane, -1.f);
    XF[base + lane]      = d[lane];
    XF[base + lane + 64] = d[lane + 64];
}

__global__ __launch_bounds__(256) void k_cols(float2* __restrict__ XF, float sign) {
    __shared__ float2 tile[HW][17];
    int img = blockIdx.x >> 3;
    int w0  = (blockIdx.x & 7) << 4;
    long base = (long)img * NPIX + w0;
    int tid = threadIdx.x;
    for (int it = 0; it < 8; ++it) {
        int flat = it * 256 + tid;
        int h = flat >> 4, c = flat & 15;
        tile[h][c] = XF[base + (long)h * HW + c];
    }
    __syncthreads();
    for (int span = 64; span >= 1; span >>= 1) {
        for (int it = 0; it < 4; ++it) {
            int idx = it * 256 + tid;
            int j = idx >> 4, c = idx & 15;
            int k = j & (span - 1);
            int bidx = ((j & ~(span - 1)) << 1) | k;
            float2 a = tile[bidx][c], b = tile[bidx + span][c];
            float2 su = make_float2(a.x + b.x, a.y + b.y);
            float2 df = make_float2(a.x - b.x, a.y - b.y);
            float rev = (float)k / (float)(2 * span);
            float cw = hw_cos(rev);
            float sw = sign * hw_sin(rev);
            tile[bidx][c] = su;
            tile[bidx + span][c] = cmulf(df, make_float2(cw, sw));
        }
        __syncthreads();
    }
    float2 v[8];
    for (int it = 0; it < 8; ++it) {
        int flat = it * 256 + tid;
        int h = flat >> 4, c = flat & 15;
        v[it] = tile[rev7(h)][c];
    }
    __syncthreads();
    for (int it = 0; it < 8; ++it) {
        int flat = it * 256 + tid;
        int h = flat >> 4, c = flat & 15;
        tile[h][c] = v[it];
    }
    __syncthreads();
    for (int it = 0; it < 8; ++it) {
        int flat = it * 256 + tid;
        int h = flat >> 4, c = flat & 15;
        XF[base + (long)h * HW + c] = tile[h][c];
    }
}

__device__ __forceinline__ void prob_to_hw(int gp, int& h, int& w) {
    if (gp < 8064)      { h = 1 + (gp >> 7); w = gp & 127; }
    else if (gp < 8129) { h = 0;  w = gp - 8064; }
    else                { h = 64; w = gp - 8129; }
}

// pixel (h,w) -> (representative problem gp, conjugate flag)
__device__ __forceinline__ void pix_to_prob(int h, int w, int& gp, bool& cj) {
    if (h >= 1 && h <= 63)      { gp = (h - 1) * 128 + w; cj = false; }
    else if (h >= 65)           { gp = (127 - h) * 128 + ((128 - w) & 127); cj = true; }
    else if (h == 0)            { if (w <= 64) { gp = 8064 + w; cj = false; }
                                  else        { gp = 8064 + 128 - w; cj = true; } }
    else                        { if (w <= 64) { gp = 8129 + w; cj = false; }
                                  else        { gp = 8129 + 128 - w; cj = true; } }
}

// build rows [rh*16, rh*16+16) of K column `col`: b[j] = K_{rh*16+j, col}(h,w)
__device__ __forceinline__ void build_kcol_half(const float* __restrict__ ker,
                                                int h, int w, int col, int rh, float2* b) {
    float twr[9], twi[9];
    #pragma unroll
    for (int u = 0; u < 3; ++u)
        #pragma unroll
        for (int v = 0; v < 3; ++v) {
            int idx = (h * u + w * v) & 127;
            float rev = (float)idx * (1.0f / 128.0f);
            twr[u * 3 + v] =  hw_cos(rev);
            twi[u * 3 + v] = -hw_sin(rev);
        }
    #pragma unroll
    for (int j = 0; j < 16; ++j) {
        int o = (rh << 4) + j;
        const float* kp = ker + (size_t)(o * NCH + col) * 9;
        float ar = 0.f, ai = 0.f;
        #pragma unroll
        for (int t = 0; t < 9; ++t) { float kv = kp[t]; ar = fmaf(kv, twr[t], ar); ai = fmaf(kv, twi[t], ai); }
        b[j] = make_float2(ar, ai);
    }
}

__device__ __forceinline__ float halfsum(float v) {
    v += __shfl_xor(v, 1);  v += __shfl_xor(v, 2);  v += __shfl_xor(v, 4);
    v += __shfl_xor(v, 8);  v += __shfl_xor(v, 16);
    return v;
}
__device__ __forceinline__ float wsum64(float v) {
    v = halfsum(v); v += __shfl_xor(v, 32);
    return v;
}

// One-sided Jacobi SVD per pixel (eig only — no XF access). 64 lanes/problem:
// lane (rh,col) owns rows [rh*16,rh*16+16) of column col. 4 problems per block.
// DS-traffic-optimized round: partner column fetched ONCE into registers
// (reused by Gram + rotation apply), column norms tracked analytically
// (app' = app - t|g|, aqq' = aqq + t|g|) instead of recomputed.
__global__ __launch_bounds__(256, 1) void k_eig2(
    const float* __restrict__ ker, const float* __restrict__ bias,
    float2* __restrict__ Uws, float* __restrict__ distP, float* __restrict__ biasp)
{
    __shared__ float2 U[4][16][33];   // per-wave slice for dist/bias tail

    int tid  = threadIdx.x;
    int wv   = tid >> 6;
    int l64  = tid & 63;
    int rh   = l64 >> 5;
    int col  = l64 & 31;
    int sbase = rh << 5;

    int gp = blockIdx.x * 4 + wv;
    bool active = gp < NPROB;
    int gpe = active ? gp : 0;
    int h, w; prob_to_hw(gpe, h, w);
    int hc = (128 - h) & 127, wc = (128 - w) & 127;
    bool self = (hc == h && wc == w);

    float2 b[16];
    build_kcol_half(ker, h, w, col, rh, b);

    // tracked column norm^2 (identical across rh halves by construction)
    float cn;
    {
        float nr = 0.f;
        #pragma unroll
        for (int i = 0; i < 16; ++i) nr = fmaf(b[i].x, b[i].x, fmaf(b[i].y, b[i].y, nr));
        cn = nr + __shfl_xor(nr, 32, 64);
    }

    // ---- one-sided Jacobi, XOR-pair ordering over columns ----
    for (int sweep = 0; sweep < 8; ++sweep) {
        float offacc = 0.f;
        for (int m = 1; m < 32; ++m) {
            bool isP = col < (col ^ m);
            // fetch partner half-column ONCE into registers
            float fx[16], fy[16];
            #pragma unroll
            for (int i = 0; i < 16; ++i) {
                fx[i] = __shfl_xor(b[i].x, m, 64);
                fy[i] = __shfl_xor(b[i].y, m, 64);
            }
            float nf = __shfl_xor(cn, m, 64);
            // partial Gram over own 16 rows; symmetric accumulators ->
            // all 4 lanes of a pair-group get bitwise-identical values.
            float gre = 0.f, A = 0.f, Bm = 0.f;
            #pragma unroll
            for (int i = 0; i < 16; ++i) {
                gre = fmaf(b[i].x, fx[i], fmaf(b[i].y, fy[i], gre));
                A   = fmaf(b[i].x, fy[i], A);
                Bm  = fmaf(b[i].y, fx[i], Bm);
            }
            gre += __shfl_xor(gre, 32, 64);
            A   += __shfl_xor(A,   32, 64);
            Bm  += __shfl_xor(Bm,  32, 64);
            float app = isP ? cn : nf;
            float aqq = isP ? nf : cn;
            float gim = isP ? (A - Bm) : (Bm - A);
            float n2 = gre * gre + gim * gim;
            offacc += n2;

            bool doRot = (n2 > 1e-24f * app * aqq) && (n2 > 1e-36f);
            if (__ballot(doRot)) {
                float ad  = sqrtf(n2);
                float tau = (aqq - app) / (2.f * ad);
                float tt  = (tau >= 0.f ? 1.f : -1.f) / (fabsf(tau) + sqrtf(fmaf(tau, tau, 1.f)));
                float cc  = rsqrtf(fmaf(tt, tt, 1.f));
                float sg  = tt * cc / ad;
                float ssx = sg * gre, ssy = sg * gim;
                float gx  = isP ? -ssx : ssx;
                float gy  = ssy;
                float dlt = tt * ad;           // diagonal shift: app-=dlt, aqq+=dlt
                if (!doRot) { cc = 1.f; gx = 0.f; gy = 0.f; dlt = 0.f; }
                #pragma unroll
                for (int i = 0; i < 16; ++i) {
                    b[i].x = fmaf(cc, b[i].x, fmaf(gx, fx[i], -gy * fy[i]));
                    b[i].y = fmaf(cc, b[i].y, fmaf(gx, fy[i],  gy * fx[i]));
                }
                cn += isP ? -dlt : dlt;
            }
        }
        // convergence: sum|g|^2 (pair-double-counted) <= 1e-10 * sum(sigma^4)
        float dg   = halfsum(cn * cn);
        float offT = halfsum(offacc);
        if (!__ballot(offT > 1e-10f * dg)) break;
    }

    // ---- top-16 selection by EXACT column norm; write normalized U ----
    float nr = 0.f;
    #pragma unroll
    for (int i = 0; i < 16; ++i) nr = fmaf(b[i].x, b[i].x, fmaf(b[i].y, b[i].y, nr));
    float nrF = nr + __shfl_xor(nr, 32, 64);
    int rank = 0;
    #pragma unroll
    for (int k = 0; k < 32; ++k) {
        float nk = __shfl(nrF, k, 64);
        if (nk > nrF || (nk == nrF && k < col)) ++rank;
    }
    bool sel = rank < 16;
    unsigned long long ball = __ballot(sel);
    unsigned cmask = (unsigned)(ball & 0xFFFFFFFFull);
    int rsel = __popc(cmask & ((1u << col) - 1u));
    float rin = rsqrtf(fmaxf(nrF, 1e-30f));
    if (sel) {
        #pragma unroll
        for (int j = 0; j < 16; ++j) {
            float2 uv = make_float2(b[j].x * rin, b[j].y * rin);
            U[wv][rsel][(rh << 4) + j] = uv;
            if (active) Uws[((size_t)gp * 16 + rsel) * 32 + (rh << 4) + j] = uv;
        }
    }
    asm volatile("s_waitcnt lgkmcnt(0)" ::: "memory");
    __builtin_amdgcn_sched_barrier(0);

    // ---- dist: ||K-P||^2 = ||K||^2 - 2 Re tr(K^H P) + 16 ----
    build_kcol_half(ker, h, w, col, rh, b);
    float kn = 0.f;
    #pragma unroll
    for (int j = 0; j < 16; ++j) kn = fmaf(b[j].x, b[j].x, fmaf(b[j].y, b[j].y, kn));
    float knt = wsum64(kn);
    float tr = 0.f;                            // both rh halves count -> 2x
    #pragma unroll
    for (int m = 0; m < 16; ++m) {
        float2 acc = make_float2(0.f, 0.f);
        #pragma unroll
        for (int j = 0; j < 16; ++j) {
            float2 um = U[wv][m][(rh << 4) + j];
            acc.x = fmaf(b[j].x, um.x, fmaf( b[j].y, um.y, acc.x));
            acc.y = fmaf(b[j].x, um.y, fmaf(-b[j].y, um.x, acc.y));
        }
        acc.x += __shfl_xor(acc.x, 32, 64);
        acc.y += __shfl_xor(acc.y, 32, 64);
        float2 w0 = U[wv][m][col];
        tr = fmaf(w0.x, acc.x, fmaf(w0.y, acc.y, tr));
    }
    float trt = wsum64(tr);                    // = 2 * Re tr(K^H P)
    if (active && l64 == 0) {
        float d2 = knt - trt + 16.f;
        distP[gp] = (self ? 1.f : 2.f) * d2;
    }

    // ---- bias correction at DC pixel (gp==8064 -> (h,w)=(0,0)) ----
    if (active && gp == 8064) {
        int mmode = col & 15;
        float2 d = make_float2(0.f, 0.f);
        #pragma unroll
        for (int j = 0; j < 16; ++j) {
            int i = (rh << 4) + j;
            float bv = bias[i];
            float2 ul = U[wv][mmode][i];
            d.x = fmaf(ul.x, bv, d.x);
            d.y = fmaf(-ul.y, bv, d.y);
        }
        d.x += __shfl_xor(d.x, 32, 64);
        d.y += __shfl_xor(d.y, 32, 64);
        float racc = 0.f;
        #pragma unroll
        for (int mm = 0; mm < 16; ++mm) {
            float dx = __shfl(d.x, sbase + mm, 64);
            float dy = __shfl(d.y, sbase + mm, 64);
            float2 ul = U[wv][mm][col];
            racc = fmaf(ul.x, dx, fmaf(-ul.y, dy, racc));
        }
        if (rh == 0) biasp[col] = bias[col] - racc;
    }
}

// Apply y_f = conj(P) x_f per pixel, rank-16 form. 8 consecutive pixels per
// block (one 64B line per (b,c) row -> coalesced). U staged in LDS.
// direct: y = conj(U)(U^T x); conj-pixel: y = U (U^H x).
__global__ __launch_bounds__(256) void k_apply(const float2* __restrict__ Uws,
                                               float2* __restrict__ XF)
{
    __shared__ float2 Us[16][33][9];   // [m][i][slot] (pads kill 8-way conflicts)
    __shared__ float2 xs[32][9];       // [c][slot]
    __shared__ float2 ts[16][9];       // [m][slot]

    int tid = threadIdx.x;
    int pb = blockIdx.x * 8;
    int h = pb >> 7, w0 = pb & 127;

    // --- stage U for the 8 pixels of this block ---
    {
        int slot = tid >> 5, t5 = tid & 31;
        int gp; bool cj;
        pix_to_prob(h, w0 + slot, gp, cj);
        size_t gbase = (size_t)gp * 512 + (size_t)t5 * 16;
        #pragma unroll
        for (int j = 0; j < 16; ++j) {
            int e = t5 * 16 + j;
            Us[e >> 5][e & 31][slot] = Uws[gbase + j];
        }
    }
    __syncthreads();

    int c = tid >> 3, ws = tid & 7;
    int gp; bool cj;
    pix_to_prob(h, w0 + ws, gp, cj);
    float sgn = cj ? -1.f : 1.f;
    long pbase = (long)h * 128 + (w0 + ws);

    for (int bb = 0; bb < NB; ++bb) {
        long adr = ((long)(bb * NCH + c)) * NPIX + pbase;
        xs[c][ws] = XF[adr];
        __syncthreads();
        if (c < 16) {
            float2 t = make_float2(0.f, 0.f);
            #pragma unroll
            for (int i = 0; i < 32; ++i) {
                float2 ul = Us[c][i][ws];
                float uy = sgn * ul.y;
                float2 xr = xs[i][ws];
                t.x = fmaf(ul.x, xr.x, fmaf(-uy, xr.y, t.x));
                t.y = fmaf(ul.x, xr.y, fmaf( uy, xr.x, t.y));
            }
            ts[c][ws] = t;
        }
        __syncthreads();
        float2 y = make_float2(0.f, 0.f);
        #pragma unroll
        for (int m = 0; m < 16; ++m) {
            float2 ul = Us[m][c][ws];
            float uy = sgn * ul.y;
            float2 t = ts[m][ws];
            y.x = fmaf(ul.x, t.x, fmaf( uy, t.y, y.x));
            y.y = fmaf(ul.x, t.y, fmaf(-uy, t.x, y.y));
        }
        XF[adr] = y;
        __syncthreads();
    }
}

__global__ __launch_bounds__(256) void k_inv_rows_bias(const float2* __restrict__ XF,
                                                       const float* __restrict__ biasp,
                                                       float* __restrict__ out) {
    __shared__ float2 buf[4][HW];
    int wave = threadIdx.x >> 6, lane = threadIdx.x & 63;
    long row = (long)blockIdx.x * 4 + wave;     // (b,o,h)
    int o = (int)((row >> 7) & 31);
    float bp = biasp[o];
    long base = row * HW;
    float2* d = buf[wave];
    d[lane]      = XF[base + lane];
    d[lane + 64] = XF[base + lane + 64];
    __syncthreads();
    fft128(d, lane, +1.f);
    const float sc = 1.0f / 128.0f;
    out[base + lane]      = d[lane].x * sc + bp;
    out[base + lane + 64] = d[lane + 64].x * sc + bp;
}

__global__ __launch_bounds__(256) void k_dist(const float* __restrict__ distP,
                                              float* __restrict__ out) {
    __shared__ float sh[256];
    float acc = 0.f;
    for (int i = threadIdx.x; i < NPROB; i += 256) acc += distP[i];
    sh[threadIdx.x] = acc;
    __syncthreads();
    for (int s = 128; s >= 1; s >>= 1) {
        if (threadIdx.x < s) sh[threadIdx.x] += sh[threadIdx.x + s];
        __syncthreads();
    }
    if (threadIdx.x == 0) out[(size_t)NB * NCH * NPIX] = sqrtf(sh[0]);
}

extern "C" void kernel_launch(void* const* d_in, const int* in_sizes, int n_in,
                              void* d_out, int out_size, void* d_ws, size_t ws_size,
                              hipStream_t stream) {
    (void)in_sizes; (void)n_in; (void)out_size; (void)ws_size;
    const float* x    = (const float*)d_in[0];
    const float* ker  = (const float*)d_in[1];
    const float* bias = (const float*)d_in[2];
    float* out = (float*)d_out;

    // ws: XF complex [16][32][128][128] (64 MiB) | distP [8194] | biasp [32]
    float2* XF   = (float2*)d_ws;
    float* distP = (float*)((char*)d_ws + (size_t)NB * NCH * NPIX * sizeof(float2));
    float* biasp = distP + NPROB;
    // U scratch in the tail of d_out (33.6 MB at +96 MB; overwritten later by
    // k_inv_rows_bias, which runs after k_apply has consumed it — stream order).
    float2* Uws = (float2*)((char*)d_out + ((size_t)96 << 20));

    int rows = NB * NCH * HW;   // 65536
    k_fwd_rows<<<dim3(rows / 4), dim3(256), 0, stream>>>(x, XF);
    k_cols<<<dim3(NB * NCH * 8), dim3(256), 0, stream>>>(XF, -1.f);
    k_eig2<<<dim3((NPROB + 3) / 4), dim3(256), 0, stream>>>(ker, bias, Uws, distP, biasp);
    k_apply<<<dim3(NPIX / 8), dim3(256), 0, stream>>>(Uws, XF);
    k_cols<<<dim3(NB * NCH * 8), dim3(256), 0, stream>>>(XF, +1.f);
    k_inv_rows_bias<<<dim3(rows / 4), dim3(256), 0, stream>>>(XF, biasp, out);
    k_dist<<<dim3(1), dim3(256), 0, stream>>>(distP, out);
}

// Round 8
// 1095.255 us; speedup vs baseline: 2.4356x; 1.0296x over previous
//
#include <hip/hip_runtime.h>
#include <math.h>

#define NCH 32
#define NB  16
#define HW  128
#define NPIX (HW*HW)
#define NPROB 8194

__device__ __forceinline__ float2 cmulf(float2 a, float2 b) {
    return make_float2(a.x*b.x - a.y*b.y, a.x*b.y + a.y*b.x);
}
__device__ __forceinline__ int rev7(int i) { return (int)(__brev((unsigned)i) >> 25); }
// HW trig: input in revolutions (angle/2pi). Exact for dyadic-rational inputs.
__device__ __forceinline__ float hw_sin(float rev) { return __builtin_amdgcn_sinf(rev); }
__device__ __forceinline__ float hw_cos(float rev) { return __builtin_amdgcn_cosf(rev); }

// 128-point radix-2 DIF FFT in LDS; 64 lanes cooperate on one transform.
__device__ void fft128(float2* d, int lane, float sign) {
    for (int span = 64; span >= 1; span >>= 1) {
        int k = lane & (span - 1);
        int base = ((lane & ~(span - 1)) << 1) | k;
        float2 a = d[base];
        float2 b = d[base + span];
        float2 su = make_float2(a.x + b.x, a.y + b.y);
        float2 df = make_float2(a.x - b.x, a.y - b.y);
        float rev = (float)k / (float)(2 * span);
        float cw = hw_cos(rev);
        float sw = sign * hw_sin(rev);
        d[base] = su;
        d[base + span] = cmulf(df, make_float2(cw, sw));
        __syncthreads();
    }
    float2 v0 = d[rev7(lane)];
    float2 v1 = d[rev7(lane + 64)];
    __syncthreads();
    d[lane] = v0;
    d[lane + 64] = v1;
    __syncthreads();
}

__global__ __launch_bounds__(256) void k_fwd_rows(const float* __restrict__ x,
                                                  float2* __restrict__ XF) {
    __shared__ float2 buf[4][HW];
    int wave = threadIdx.x >> 6, lane = threadIdx.x & 63;
    long row = (long)blockIdx.x * 4 + wave;
    long base = row * HW;
    const float sc = 1.0f / 128.0f;
    float2* d = buf[wave];
    d[lane]      = make_float2(x[base + lane] * sc, 0.f);
    d[lane + 64] = make_float2(x[base + lane + 64] * sc, 0.f);
    __syncthreads();
    fft128(d, lane, -1.f);
    XF[base + lane]      = d[lane];
    XF[base + lane + 64] = d[lane + 64];
}

__global__ __launch_bounds__(256) void k_cols(float2* __restrict__ XF, float sign) {
    __shared__ float2 tile[HW][17];
    int img = blockIdx.x >> 3;
    int w0  = (blockIdx.x & 7) << 4;
    long base = (long)img * NPIX + w0;
    int tid = threadIdx.x;
    for (int it = 0; it < 8; ++it) {
        int flat = it * 256 + tid;
        int h = flat >> 4, c = flat & 15;
        tile[h][c] = XF[base + (long)h * HW + c];
    }
    __syncthreads();
    for (int span = 64; span >= 1; span >>= 1) {
        for (int it = 0; it < 4; ++it) {
            int idx = it * 256 + tid;
            int j = idx >> 4, c = idx & 15;
            int k = j & (span - 1);
            int bidx = ((j & ~(span - 1)) << 1) | k;
            float2 a = tile[bidx][c], b = tile[bidx + span][c];
            float2 su = make_float2(a.x + b.x, a.y + b.y);
            float2 df = make_float2(a.x - b.x, a.y - b.y);
            float rev = (float)k / (float)(2 * span);
            float cw = hw_cos(rev);
            float sw = sign * hw_sin(rev);
            tile[bidx][c] = su;
            tile[bidx + span][c] = cmulf(df, make_float2(cw, sw));
        }
        __syncthreads();
    }
    float2 v[8];
    for (int it = 0; it < 8; ++it) {
        int flat = it * 256 + tid;
        int h = flat >> 4, c = flat & 15;
        v[it] = tile[rev7(h)][c];
    }
    __syncthreads();
    for (int it = 0; it < 8; ++it) {
        int flat = it * 256 + tid;
        int h = flat >> 4, c = flat & 15;
        tile[h][c] = v[it];
    }
    __syncthreads();
    for (int it = 0; it < 8; ++it) {
        int flat = it * 256 + tid;
        int h = flat >> 4, c = flat & 15;
        XF[base + (long)h * HW + c] = tile[h][c];
    }
}

__device__ __forceinline__ void prob_to_hw(int gp, int& h, int& w) {
    if (gp < 8064)      { h = 1 + (gp >> 7); w = gp & 127; }
    else if (gp < 8129) { h = 0;  w = gp - 8064; }
    else                { h = 64; w = gp - 8129; }
}

// pixel (h,w) -> (representative problem gp, conjugate flag)
__device__ __forceinline__ void pix_to_prob(int h, int w, int& gp, bool& cj) {
    if (h >= 1 && h <= 63)      { gp = (h - 1) * 128 + w; cj = false; }
    else if (h >= 65)           { gp = (127 - h) * 128 + ((128 - w) & 127); cj = true; }
    else if (h == 0)            { if (w <= 64) { gp = 8064 + w; cj = false; }
                                  else        { gp = 8064 + 128 - w; cj = true; } }
    else                        { if (w <= 64) { gp = 8129 + w; cj = false; }
                                  else        { gp = 8129 + 128 - w; cj = true; } }
}

// build rows [rh*16, rh*16+16) of K column `col`: b[j] = K_{rh*16+j, col}(h,w)
__device__ __forceinline__ void build_kcol_half(const float* __restrict__ ker,
                                                int h, int w, int col, int rh, float2* b) {
    float twr[9], twi[9];
    #pragma unroll
    for (int u = 0; u < 3; ++u)
        #pragma unroll
        for (int v = 0; v < 3; ++v) {
            int idx = (h * u + w * v) & 127;
            float rev = (float)idx * (1.0f / 128.0f);
            twr[u * 3 + v] =  hw_cos(rev);
            twi[u * 3 + v] = -hw_sin(rev);
        }
    #pragma unroll
    for (int j = 0; j < 16; ++j) {
        int o = (rh << 4) + j;
        const float* kp = ker + (size_t)(o * NCH + col) * 9;
        float ar = 0.f, ai = 0.f;
        #pragma unroll
        for (int t = 0; t < 9; ++t) { float kv = kp[t]; ar = fmaf(kv, twr[t], ar); ai = fmaf(kv, twi[t], ai); }
        b[j] = make_float2(ar, ai);
    }
}

__device__ __forceinline__ float halfsum(float v) {
    v += __shfl_xor(v, 1);  v += __shfl_xor(v, 2);  v += __shfl_xor(v, 4);
    v += __shfl_xor(v, 8);  v += __shfl_xor(v, 16);
    return v;
}
__device__ __forceinline__ float wsum64(float v) {
    v = halfsum(v); v += __shfl_xor(v, 32);
    return v;
}

// One-sided Jacobi SVD per pixel. ONE problem per 64-thread block (1 wave):
// waves retire independently (no multi-wave LDS stranding), LDS 4.2KB/block.
// lane (rh,col) owns rows [rh*16,rh*16+16) of column col. Partner column
// fetched once per round into registers; column norms tracked analytically.
__global__ __launch_bounds__(64, 1) void k_eig3(
    const float* __restrict__ ker, const float* __restrict__ bias,
    float2* __restrict__ Uws, float* __restrict__ distP, float* __restrict__ biasp)
{
    __shared__ float2 U[16][33];      // selected columns, transposed access

    int l64  = threadIdx.x & 63;
    int rh   = l64 >> 5;
    int col  = l64 & 31;
    int sbase = rh << 5;

    int gp = blockIdx.x;              // grid == NPROB exactly
    int h, w; prob_to_hw(gp, h, w);
    int hc = (128 - h) & 127, wc = (128 - w) & 127;
    bool self = (hc == h && wc == w);

    float2 b[16];
    build_kcol_half(ker, h, w, col, rh, b);

    // tracked column norm^2 (identical across rh halves by construction)
    float cn;
    {
        float nr = 0.f;
        #pragma unroll
        for (int i = 0; i < 16; ++i) nr = fmaf(b[i].x, b[i].x, fmaf(b[i].y, b[i].y, nr));
        cn = nr + __shfl_xor(nr, 32, 64);
    }

    // ---- one-sided Jacobi, XOR-pair ordering over columns ----
    for (int sweep = 0; sweep < 8; ++sweep) {
        float offacc = 0.f;
        for (int m = 1; m < 32; ++m) {
            bool isP = col < (col ^ m);
            // fetch partner half-column ONCE into registers
            float fx[16], fy[16];
            #pragma unroll
            for (int i = 0; i < 16; ++i) {
                fx[i] = __shfl_xor(b[i].x, m, 64);
                fy[i] = __shfl_xor(b[i].y, m, 64);
            }
            float nf = __shfl_xor(cn, m, 64);
            // partial Gram over own 16 rows; symmetric accumulators ->
            // all 4 lanes of a pair-group get bitwise-identical values.
            float gre = 0.f, A = 0.f, Bm = 0.f;
            #pragma unroll
            for (int i = 0; i < 16; ++i) {
                gre = fmaf(b[i].x, fx[i], fmaf(b[i].y, fy[i], gre));
                A   = fmaf(b[i].x, fy[i], A);
                Bm  = fmaf(b[i].y, fx[i], Bm);
            }
            gre += __shfl_xor(gre, 32, 64);
            A   += __shfl_xor(A,   32, 64);
            Bm  += __shfl_xor(Bm,  32, 64);
            float app = isP ? cn : nf;
            float aqq = isP ? nf : cn;
            float gim = isP ? (A - Bm) : (Bm - A);
            float n2 = gre * gre + gim * gim;
            offacc += n2;

            bool doRot = (n2 > 1e-24f * app * aqq) && (n2 > 1e-36f);
            if (__ballot(doRot)) {
                float ad  = sqrtf(n2);
                float tau = (aqq - app) / (2.f * ad);
                float tt  = (tau >= 0.f ? 1.f : -1.f) / (fabsf(tau) + sqrtf(fmaf(tau, tau, 1.f)));
                float cc  = rsqrtf(fmaf(tt, tt, 1.f));
                float sg  = tt * cc / ad;
                float ssx = sg * gre, ssy = sg * gim;
                float gx  = isP ? -ssx : ssx;
                float gy  = ssy;
                float dlt = tt * ad;           // diagonal shift: app-=dlt, aqq+=dlt
                if (!doRot) { cc = 1.f; gx = 0.f; gy = 0.f; dlt = 0.f; }
                #pragma unroll
                for (int i = 0; i < 16; ++i) {
                    b[i].x = fmaf(cc, b[i].x, fmaf(gx, fx[i], -gy * fy[i]));
                    b[i].y = fmaf(cc, b[i].y, fmaf(gx, fy[i],  gy * fx[i]));
                }
                cn += isP ? -dlt : dlt;
            }
        }
        // convergence: sum|g|^2 (pair-double-counted) <= 1e-8 * sum(sigma^4)
        float dg   = halfsum(cn * cn);
        float offT = halfsum(offacc);
        if (!__ballot(offT > 1e-8f * dg)) break;
    }

    // ---- top-16 selection by EXACT column norm; write normalized U ----
    float nr = 0.f;
    #pragma unroll
    for (int i = 0; i < 16; ++i) nr = fmaf(b[i].x, b[i].x, fmaf(b[i].y, b[i].y, nr));
    float nrF = nr + __shfl_xor(nr, 32, 64);
    int rank = 0;
    #pragma unroll
    for (int k = 0; k < 32; ++k) {
        float nk = __shfl(nrF, k, 64);
        if (nk > nrF || (nk == nrF && k < col)) ++rank;
    }
    bool sel = rank < 16;
    unsigned long long ball = __ballot(sel);
    unsigned cmask = (unsigned)(ball & 0xFFFFFFFFull);
    int rsel = __popc(cmask & ((1u << col) - 1u));
    float rin = rsqrtf(fmaxf(nrF, 1e-30f));
    if (sel) {
        #pragma unroll
        for (int j = 0; j < 16; ++j) {
            float2 uv = make_float2(b[j].x * rin, b[j].y * rin);
            U[rsel][(rh << 4) + j] = uv;
            Uws[((size_t)gp * 16 + rsel) * 32 + (rh << 4) + j] = uv;
        }
    }
    asm volatile("s_waitcnt lgkmcnt(0)" ::: "memory");
    __builtin_amdgcn_sched_barrier(0);

    // ---- dist: ||K-P||^2 = ||K||^2 - 2 Re tr(K^H P) + 16 ----
    build_kcol_half(ker, h, w, col, rh, b);
    float kn = 0.f;
    #pragma unroll
    for (int j = 0; j < 16; ++j) kn = fmaf(b[j].x, b[j].x, fmaf(b[j].y, b[j].y, kn));
    float knt = wsum64(kn);
    float tr = 0.f;                            // both rh halves count -> 2x
    #pragma unroll
    for (int m = 0; m < 16; ++m) {
        float2 acc = make_float2(0.f, 0.f);
        #pragma unroll
        for (int j = 0; j < 16; ++j) {
            float2 um = U[m][(rh << 4) + j];
            acc.x = fmaf(b[j].x, um.x, fmaf( b[j].y, um.y, acc.x));
            acc.y = fmaf(b[j].x, um.y, fmaf(-b[j].y, um.x, acc.y));
        }
        acc.x += __shfl_xor(acc.x, 32, 64);
        acc.y += __shfl_xor(acc.y, 32, 64);
        float2 w0 = U[m][col];
        tr = fmaf(w0.x, acc.x, fmaf(w0.y, acc.y, tr));
    }
    float trt = wsum64(tr);                    // = 2 * Re tr(K^H P)
    if (l64 == 0) {
        float d2 = knt - trt + 16.f;
        distP[gp] = (self ? 1.f : 2.f) * d2;
    }

    // ---- bias correction at DC pixel (gp==8064 -> (h,w)=(0,0)) ----
    if (gp == 8064) {
        int mmode = col & 15;
        float2 d = make_float2(0.f, 0.f);
        #pragma unroll
        for (int j = 0; j < 16; ++j) {
            int i = (rh << 4) + j;
            float bv = bias[i];
            float2 ul = U[mmode][i];
            d.x = fmaf(ul.x, bv, d.x);
            d.y = fmaf(-ul.y, bv, d.y);
        }
        d.x += __shfl_xor(d.x, 32, 64);
        d.y += __shfl_xor(d.y, 32, 64);
        float racc = 0.f;
        #pragma unroll
        for (int mm = 0; mm < 16; ++mm) {
            float dx = __shfl(d.x, sbase + mm, 64);
            float dy = __shfl(d.y, sbase + mm, 64);
            float2 ul = U[mm][col];
            racc = fmaf(ul.x, dx, fmaf(-ul.y, dy, racc));
        }
        if (rh == 0) biasp[col] = bias[col] - racc;
    }
}

// Apply y_f = conj(P) x_f per pixel, rank-16 form. 8 consecutive pixels per
// block (one 64B line per (b,c) row -> coalesced). U staged in LDS.
// direct: y = conj(U)(U^T x); conj-pixel: y = U (U^H x).
__global__ __launch_bounds__(256) void k_apply(const float2* __restrict__ Uws,
                                               float2* __restrict__ XF)
{
    __shared__ float2 Us[16][33][9];   // [m][i][slot] (pads kill 8-way conflicts)
    __shared__ float2 xs[32][9];       // [c][slot]
    __shared__ float2 ts[16][9];       // [m][slot]

    int tid = threadIdx.x;
    int pb = blockIdx.x * 8;
    int h = pb >> 7, w0 = pb & 127;

    // --- stage U for the 8 pixels of this block ---
    {
        int slot = tid >> 5, t5 = tid & 31;
        int gp; bool cj;
        pix_to_prob(h, w0 + slot, gp, cj);
        size_t gbase = (size_t)gp * 512 + (size_t)t5 * 16;
        #pragma unroll
        for (int j = 0; j < 16; ++j) {
            int e = t5 * 16 + j;
            Us[e >> 5][e & 31][slot] = Uws[gbase + j];
        }
    }
    __syncthreads();

    int c = tid >> 3, ws = tid & 7;
    int gp; bool cj;
    pix_to_prob(h, w0 + ws, gp, cj);
    float sgn = cj ? -1.f : 1.f;
    long pbase = (long)h * 128 + (w0 + ws);

    for (int bb = 0; bb < NB; ++bb) {
        long adr = ((long)(bb * NCH + c)) * NPIX + pbase;
        xs[c][ws] = XF[adr];
        __syncthreads();
        if (c < 16) {
            float2 t = make_float2(0.f, 0.f);
            #pragma unroll
            for (int i = 0; i < 32; ++i) {
                float2 ul = Us[c][i][ws];
                float uy = sgn * ul.y;
                float2 xr = xs[i][ws];
                t.x = fmaf(ul.x, xr.x, fmaf(-uy, xr.y, t.x));
                t.y = fmaf(ul.x, xr.y, fmaf( uy, xr.x, t.y));
            }
            ts[c][ws] = t;
        }
        __syncthreads();
        float2 y = make_float2(0.f, 0.f);
        #pragma unroll
        for (int m = 0; m < 16; ++m) {
            float2 ul = Us[m][c][ws];
            float uy = sgn * ul.y;
            float2 t = ts[m][ws];
            y.x = fmaf(ul.x, t.x, fmaf( uy, t.y, y.x));
            y.y = fmaf(ul.x, t.y, fmaf(-uy, t.x, y.y));
        }
        XF[adr] = y;
        __syncthreads();
    }
}

__global__ __launch_bounds__(256) void k_inv_rows_bias(const float2* __restrict__ XF,
                                                       const float* __restrict__ biasp,
                                                       float* __restrict__ out) {
    __shared__ float2 buf[4][HW];
    int wave = threadIdx.x >> 6, lane = threadIdx.x & 63;
    long row = (long)blockIdx.x * 4 + wave;     // (b,o,h)
    int o = (int)((row >> 7) & 31);
    float bp = biasp[o];
    long base = row * HW;
    float2* d = buf[wave];
    d[lane]      = XF[base + lane];
    d[lane + 64] = XF[base + lane + 64];
    __syncthreads();
    fft128(d, lane, +1.f);
    const float sc = 1.0f / 128.0f;
    out[base + lane]      = d[lane].x * sc + bp;
    out[base + lane + 64] = d[lane + 64].x * sc + bp;
}

__global__ __launch_bounds__(256) void k_dist(const float* __restrict__ distP,
                                              float* __restrict__ out) {
    __shared__ float sh[256];
    float acc = 0.f;
    for (int i = threadIdx.x; i < NPROB; i += 256) acc += distP[i];
    sh[threadIdx.x] = acc;
    __syncthreads();
    for (int s = 128; s >= 1; s >>= 1) {
        if (threadIdx.x < s) sh[threadIdx.x] += sh[threadIdx.x + s];
        __syncthreads();
    }
    if (threadIdx.x == 0) out[(size_t)NB * NCH * NPIX] = sqrtf(sh[0]);
}

extern "C" void kernel_launch(void* const* d_in, const int* in_sizes, int n_in,
                              void* d_out, int out_size, void* d_ws, size_t ws_size,
                              hipStream_t stream) {
    (void)in_sizes; (void)n_in; (void)out_size; (void)ws_size;
    const float* x    = (const float*)d_in[0];
    const float* ker  = (const float*)d_in[1];
    const float* bias = (const float*)d_in[2];
    float* out = (float*)d_out;

    // ws: XF complex [16][32][128][128] (64 MiB) | distP [8194] | biasp [32]
    float2* XF   = (float2*)d_ws;
    float* distP = (float*)((char*)d_ws + (size_t)NB * NCH * NPIX * sizeof(float2));
    float* biasp = distP + NPROB;
    // U scratch in the tail of d_out (33.6 MB at +96 MB; overwritten later by
    // k_inv_rows_bias, which runs after k_apply has consumed it — stream order).
    float2* Uws = (float2*)((char*)d_out + ((size_t)96 << 20));

    int rows = NB * NCH * HW;   // 65536
    k_fwd_rows<<<dim3(rows / 4), dim3(256), 0, stream>>>(x, XF);
    k_cols<<<dim3(NB * NCH * 8), dim3(256), 0, stream>>>(XF, -1.f);
    k_eig3<<<dim3(NPROB), dim3(64), 0, stream>>>(ker, bias, Uws, distP, biasp);
    k_apply<<<dim3(NPIX / 8), dim3(256), 0, stream>>>(Uws, XF);
    k_cols<<<dim3(NB * NCH * 8), dim3(256), 0, stream>>>(XF, +1.f);
    k_inv_rows_bias<<<dim3(rows / 4), dim3(256), 0, stream>>>(XF, biasp, out);
    k_dist<<<dim3(1), dim3(256), 0, stream>>>(distP, out);
}